// Round 2
// baseline (809.487 us; speedup 1.0000x reference)
//
#include <hip/hip_runtime.h>

// ---------- constants ----------
#define NPATCH 76832   // 32 * 49 * 49
#define NBLK   601     // ceil(NPATCH/128)
#define K1     1280    // 20*8*8
#define NH     256
#define NOUT   27

typedef __attribute__((ext_vector_type(8))) short  short8;
typedef __attribute__((ext_vector_type(4))) float  floatx4;

__device__ __forceinline__ unsigned short f2b(float f) {
    unsigned int u = __builtin_bit_cast(unsigned int, f);
    u += 0x7FFFu + ((u >> 16) & 1u);   // RNE
    return (unsigned short)(u >> 16);
}
__device__ __forceinline__ float b2f(unsigned short h) {
    unsigned int u = ((unsigned int)h) << 16;
    return __builtin_bit_cast(float, u);
}

// ---------- weight fp32 -> bf16 ----------
__global__ void to_bf16(const float* __restrict__ src, unsigned short* __restrict__ dst, int n) {
    int i = blockIdx.x * 256 + threadIdx.x;
    if (i < n) dst[i] = f2b(src[i]);
}

// ---------- fused tile + conv1 + conv2 ----------
// 256 threads = 16 patches/block, 16 threads/patch, 4 pixels (half row) per thread.
// Writes X rows LOCAL to the chunk: X[(Pi - row0)][o*64 + pix].
__global__ __launch_bounds__(256, 2) void conv_fused(
    const float* __restrict__ img,
    const float* __restrict__ w1, const float* __restrict__ b1,
    const float* __restrict__ w2, const float* __restrict__ b2,
    unsigned short* __restrict__ X, int row0)
{
    __shared__ float s_w1[2 * 9 * 20];     // [c][tap][o]
    __shared__ float s_w2[20 * 9 * 20];    // [c][tap][o]
    __shared__ float s_b1[20], s_b2[20];
    __shared__ unsigned short s_h1[16][20][64];  // bf16 conv1 output

    const int tid = threadIdx.x;
    for (int d = tid; d < 360; d += 256) {
        int o = d % 20, ct = d / 20, c = ct / 9, tap = ct % 9;
        s_w1[d] = w1[o * 18 + c * 9 + tap];
    }
    for (int d = tid; d < 3600; d += 256) {
        int o = d % 20, ct = d / 20, c = ct / 9, tap = ct % 9;
        s_w2[d] = w2[o * 180 + c * 9 + tap];
    }
    if (tid < 20) { s_b1[tid] = b1[tid]; s_b2[tid] = b2[tid]; }

    const int q = tid >> 4, t = tid & 15;
    const int Pl = blockIdx.x * 16 + q;      // local row in chunk
    const int Pi = row0 + Pl;                // global patch index
    const bool valid = Pi < NPATCH;
    int b = 0, hi = 0, wi = 0;
    if (valid) { b = Pi / 2401; int rem = Pi - b * 2401; hi = rem / 49; wi = rem - hi * 49; }
    const int py = t >> 1, px0 = (t & 1) * 4;
    const float* ib = img + (long long)b * 21632 + (hi * 2) * 104 + (wi * 2);

    __syncthreads();

    // ---- conv1: acc1[4 px][20 o]
    float acc1[4][20];
    #pragma unroll
    for (int j = 0; j < 4; ++j)
        #pragma unroll
        for (int o = 0; o < 20; ++o) acc1[j][o] = s_b1[o];

    #pragma unroll
    for (int c = 0; c < 2; ++c) {
        float win[3][6];
        #pragma unroll
        for (int dy = 0; dy < 3; ++dy) {
            int ny = py + dy - 1;
            int nyc = ny < 0 ? 0 : (ny > 7 ? 7 : ny);
            #pragma unroll
            for (int dxw = 0; dxw < 6; ++dxw) {
                int nx = px0 + dxw - 1;
                int nxc = nx < 0 ? 0 : (nx > 7 ? 7 : nx);
                float v = ib[c * 10816 + nyc * 104 + nxc];   // clamped -> always in-bounds
                bool ok = valid && (ny >= 0) && (ny < 8) && (nx >= 0) && (nx < 8);
                win[dy][dxw] = ok ? v : 0.f;
            }
        }
        #pragma unroll
        for (int tap = 0; tap < 9; ++tap) {
            const int dy = tap / 3, dx = tap % 3;
            const float* wrow = &s_w1[(c * 9 + tap) * 20];
            #pragma unroll
            for (int o4 = 0; o4 < 5; ++o4) {
                floatx4 wv = *(const floatx4*)&wrow[o4 * 4];
                #pragma unroll
                for (int j = 0; j < 4; ++j)
                    #pragma unroll
                    for (int oo = 0; oo < 4; ++oo)
                        acc1[j][o4 * 4 + oo] = fmaf(win[dy][dx + j], wv[oo], acc1[j][o4 * 4 + oo]);
            }
        }
    }
    #pragma unroll
    for (int o = 0; o < 20; ++o)
        #pragma unroll
        for (int j = 0; j < 4; ++j)
            s_h1[q][o][py * 8 + px0 + j] = f2b(fmaxf(acc1[j][o], 0.f));

    __syncthreads();

    // ---- conv2
    float acc2[4][20];
    #pragma unroll
    for (int j = 0; j < 4; ++j)
        #pragma unroll
        for (int o = 0; o < 20; ++o) acc2[j][o] = s_b2[o];

    #pragma unroll 1
    for (int c = 0; c < 20; ++c) {
        float win[3][6];
        #pragma unroll
        for (int dy = 0; dy < 3; ++dy) {
            int ny = py + dy - 1;
            int nyc = ny < 0 ? 0 : (ny > 7 ? 7 : ny);
            #pragma unroll
            for (int dxw = 0; dxw < 6; ++dxw) {
                int nx = px0 + dxw - 1;
                int nxc = nx < 0 ? 0 : (nx > 7 ? 7 : nx);
                float v = b2f(s_h1[q][c][nyc * 8 + nxc]);
                bool ok = (ny >= 0) && (ny < 8) && (nx >= 0) && (nx < 8);
                win[dy][dxw] = ok ? v : 0.f;
            }
        }
        const float* wbase = &s_w2[c * 180];
        #pragma unroll
        for (int tap = 0; tap < 9; ++tap) {
            const int dy = tap / 3, dx = tap % 3;
            #pragma unroll
            for (int o4 = 0; o4 < 5; ++o4) {
                floatx4 wv = *(const floatx4*)&wbase[tap * 20 + o4 * 4];
                #pragma unroll
                for (int j = 0; j < 4; ++j)
                    #pragma unroll
                    for (int oo = 0; oo < 4; ++oo)
                        acc2[j][o4 * 4 + oo] = fmaf(win[dy][dx + j], wv[oo], acc2[j][o4 * 4 + oo]);
            }
        }
    }

    unsigned short* xrow = X + (long long)Pl * K1;
    #pragma unroll
    for (int o = 0; o < 20; ++o) {
        #pragma unroll
        for (int jp = 0; jp < 2; ++jp) {
            unsigned int lo = f2b(fmaxf(acc2[jp * 2 + 0][o], 0.f));
            unsigned int hh = f2b(fmaxf(acc2[jp * 2 + 1][o], 0.f));
            *(unsigned int*)&xrow[o * 64 + py * 8 + px0 + jp * 2] = lo | (hh << 16);
        }
    }
}

// ---------- bf16 MFMA GEMM: C[rows][256] = relu(A[rows][K] @ W[256][K]^T + bias) ----------
template<int K, bool RELU>
__global__ __launch_bounds__(256, 2) void gemm_bt(
    const unsigned short* __restrict__ A,
    const unsigned short* __restrict__ W,
    const float* __restrict__ bias,
    unsigned short* __restrict__ C)
{
    constexpr int BK = 64;
    constexpr int LDR = BK + 8;   // +16B pad
    __shared__ unsigned short s_a[128 * LDR];
    __shared__ unsigned short s_b[128 * LDR];

    const int tid = threadIdx.x;
    const int m0 = blockIdx.x * 128, n0 = blockIdx.y * 128;
    const int wave = tid >> 6, lane = tid & 63;
    const int wm = wave >> 1, wn = wave & 1;
    const int l15 = lane & 15, quad = lane >> 4;

    floatx4 acc[4][4] = {};

    #pragma unroll 1
    for (int kt = 0; kt < K; kt += BK) {
        #pragma unroll
        for (int i = 0; i < 4; ++i) {
            int chunk = tid + i * 256;            // 0..1023
            int row = chunk >> 3, kv = (chunk & 7) * 8;
            *(uint4*)&s_a[row * LDR + kv] = *(const uint4*)(A + (long long)(m0 + row) * K + kt + kv);
            *(uint4*)&s_b[row * LDR + kv] = *(const uint4*)(W + (long long)(n0 + row) * K + kt + kv);
        }
        __syncthreads();
        #pragma unroll
        for (int kh = 0; kh < 2; ++kh) {
            const int kk = kh * 32;
            short8 af[4], bf[4];
            #pragma unroll
            for (int mt = 0; mt < 4; ++mt)
                af[mt] = *(const short8*)&s_a[(wm * 64 + mt * 16 + l15) * LDR + kk + quad * 8];
            #pragma unroll
            for (int nt = 0; nt < 4; ++nt)
                bf[nt] = *(const short8*)&s_b[(wn * 64 + nt * 16 + l15) * LDR + kk + quad * 8];
            #pragma unroll
            for (int mt = 0; mt < 4; ++mt)
                #pragma unroll
                for (int nt = 0; nt < 4; ++nt)
                    acc[mt][nt] = __builtin_amdgcn_mfma_f32_16x16x32_bf16(af[mt], bf[nt], acc[mt][nt], 0, 0, 0);
        }
        __syncthreads();
    }

    #pragma unroll
    for (int nt = 0; nt < 4; ++nt) {
        const int col = n0 + wn * 64 + nt * 16 + l15;
        const float bv = bias[col];
        #pragma unroll
        for (int mt = 0; mt < 4; ++mt) {
            #pragma unroll
            for (int r = 0; r < 4; ++r) {
                int row = m0 + wm * 64 + mt * 16 + quad * 4 + r;
                float v = acc[mt][nt][r] + bv;
                if (RELU) v = fmaxf(v, 0.f);
                C[(long long)row * 256 + col] = f2b(v);
            }
        }
    }
}

// ---------- final layer: out[global rows][27] = H[.][256] @ W[27][256]^T + b (fp32) ----------
__global__ __launch_bounds__(256, 2) void fcf_kernel(
    const unsigned short* __restrict__ H,
    const float* __restrict__ W,
    const float* __restrict__ B,
    float* __restrict__ out, int row0)
{
    constexpr int LDW = 260;
    __shared__ float s_w[27 * LDW];
    __shared__ float s_bb[32];
    __shared__ unsigned short s_h[8 * 256];

    const int tid = threadIdx.x;
    for (int d = tid; d < 27 * 256; d += 256) {
        int o = d >> 8, k = d & 255;
        s_w[o * LDW + k] = W[d];
    }
    if (tid < 27) s_bb[tid] = B[tid];
    const int rl0 = blockIdx.x * 8;     // local row base in chunk
    {
        int r = tid >> 5, k8 = (tid & 31) * 8;
        *(uint4*)&s_h[r * 256 + k8] = *(const uint4*)&H[(long long)(rl0 + r) * 256 + k8];
    }
    __syncthreads();

    const int r = tid >> 5, o = tid & 31;
    const int grow = row0 + rl0 + r;
    if (o < 27 && grow < NPATCH) {
        float acc = s_bb[o];
        const unsigned short* hp = &s_h[r * 256];
        const float* wp = &s_w[o * LDW];
        #pragma unroll 4
        for (int k = 0; k < 256; k += 8) {
            short8 hv = *(const short8*)&hp[k];
            floatx4 w0 = *(const floatx4*)&wp[k];
            floatx4 w1 = *(const floatx4*)&wp[k + 4];
            acc = fmaf(b2f((unsigned short)hv[0]), w0[0], acc);
            acc = fmaf(b2f((unsigned short)hv[1]), w0[1], acc);
            acc = fmaf(b2f((unsigned short)hv[2]), w0[2], acc);
            acc = fmaf(b2f((unsigned short)hv[3]), w0[3], acc);
            acc = fmaf(b2f((unsigned short)hv[4]), w1[0], acc);
            acc = fmaf(b2f((unsigned short)hv[5]), w1[1], acc);
            acc = fmaf(b2f((unsigned short)hv[6]), w1[2], acc);
            acc = fmaf(b2f((unsigned short)hv[7]), w1[3], acc);
        }
        out[(long long)grow * 27 + o] = acc;
    }
}

extern "C" void kernel_launch(void* const* d_in, const int* in_sizes, int n_in,
                              void* d_out, int out_size, void* d_ws, size_t ws_size,
                              hipStream_t stream) {
    const float* images = (const float*)d_in[0];
    const float* c1w = (const float*)d_in[1];
    const float* c1b = (const float*)d_in[2];
    const float* c2w = (const float*)d_in[3];
    const float* c2b = (const float*)d_in[4];
    const float* f1w = (const float*)d_in[5];
    const float* f1b = (const float*)d_in[6];
    const float* f2w = (const float*)d_in[7];
    const float* f2b_ = (const float*)d_in[8];
    const float* f3w = (const float*)d_in[9];
    const float* f3b = (const float*)d_in[10];
    const float* ffw = (const float*)d_in[11];
    const float* ffb = (const float*)d_in[12];

    // ---- ws layout: [W1 bf16][W2][W3][X chunk][H1 chunk][H2 chunk] ----
    const long long W1_E = 256LL * 1280, W2_E = 256LL * 256, W3_E = 256LL * 256;
    const long long WB = (W1_E + W2_E + W3_E) * 2;          // 917504 bytes
    char* ws = (char*)d_ws;
    unsigned short* W1 = (unsigned short*)ws;
    unsigned short* W2 = W1 + W1_E;
    unsigned short* W3 = W2 + W2_E;

    // per 128-row block: X 128*1280*2 + H1 128*256*2 + H2 128*256*2 = 458752 B
    long long avail = (long long)ws_size - WB - 256;
    int nb_max = (int)(avail / 458752LL);
    if (nb_max < 1) nb_max = 1;
    if (nb_max > NBLK) nb_max = NBLK;

    unsigned short* X  = (unsigned short*)(ws + WB);
    unsigned short* H1 = X  + (long long)nb_max * 128 * K1;
    unsigned short* H2 = H1 + (long long)nb_max * 128 * NH;

    to_bf16<<<(int)((W1_E + 255) / 256), 256, 0, stream>>>(f1w, W1, (int)W1_E);
    to_bf16<<<(int)((W2_E + 255) / 256), 256, 0, stream>>>(f2w, W2, (int)W2_E);
    to_bf16<<<(int)((W3_E + 255) / 256), 256, 0, stream>>>(f3w, W3, (int)W3_E);

    for (int b0 = 0; b0 < NBLK; b0 += nb_max) {
        int nb = NBLK - b0; if (nb > nb_max) nb = nb_max;
        int row0 = b0 * 128;
        int rows = nb * 128;

        conv_fused<<<rows / 16, 256, 0, stream>>>(images, c1w, c1b, c2w, c2b, X, row0);

        gemm_bt<1280, true><<<dim3(nb, 2), 256, 0, stream>>>(X,  W1, f1b, H1);
        gemm_bt<256,  true><<<dim3(nb, 2), 256, 0, stream>>>(H1, W2, f2b_, H2);
        gemm_bt<256,  true><<<dim3(nb, 2), 256, 0, stream>>>(H2, W3, f3b, H1);  // H1 reused for h3

        fcf_kernel<<<rows / 8, 256, 0, stream>>>(H1, ffw, ffb, (float*)d_out, row0);
    }
}

// Round 3
// 558.457 us; speedup vs baseline: 1.4495x; 1.4495x over previous
//
#include <hip/hip_runtime.h>

// ---------- constants ----------
#define NPATCH 76832   // 32 * 49 * 49
#define NBLK   601     // ceil(NPATCH/128)
#define K1     1280    // 20*8*8
#define NH     256
#define NOUT   27

typedef __attribute__((ext_vector_type(8))) short  short8;
typedef __attribute__((ext_vector_type(4))) float  floatx4;

__device__ __forceinline__ unsigned short f2b(float f) {
    unsigned int u = __builtin_bit_cast(unsigned int, f);
    u += 0x7FFFu + ((u >> 16) & 1u);   // RNE
    return (unsigned short)(u >> 16);
}
__device__ __forceinline__ float b2f(unsigned short h) {
    unsigned int u = ((unsigned int)h) << 16;
    return __builtin_bit_cast(float, u);
}

// ---------- weight fp32 -> bf16 ----------
__global__ void to_bf16(const float* __restrict__ src, unsigned short* __restrict__ dst, int n) {
    int i = blockIdx.x * 256 + threadIdx.x;
    if (i < n) dst[i] = f2b(src[i]);
}

// ---------- conv2 weights -> W2T[tap][o:32][c:32] bf16 (zero-padded) ----------
__global__ void to_w2t(const float* __restrict__ w2, unsigned short* __restrict__ W2T) {
    int i = blockIdx.x * 256 + threadIdx.x;
    if (i >= 9 * 32 * 32) return;
    int tap = i >> 10, rem = i & 1023, o = rem >> 5, c = rem & 31;
    unsigned short v = 0;
    if (o < 20 && c < 20) v = f2b(w2[o * 180 + c * 9 + tap]);
    W2T[i] = v;
}

// ---------- fused tile + conv1(VALU) + conv2(MFMA tap-loop) ----------
// 256 threads = 8 patches/block. conv1: 32 thr/patch, 2 px each.
// conv2: wave w owns patches {2w, 2w+1}, 16x16x32 bf16 MFMA over 9 taps.
__global__ __launch_bounds__(256, 2) void conv_mfma(
    const float* __restrict__ img,
    const float* __restrict__ w1, const float* __restrict__ b1,
    const unsigned short* __restrict__ W2T, const float* __restrict__ b2,
    unsigned short* __restrict__ X, int row0)
{
    __shared__ float s_w1[360];                      // [c*9+tap][o]
    __shared__ float s_b1[20];
    __shared__ float s_b2[32];
    __shared__ unsigned short s_w2t[9 * 32 * 32];    // [tap][o][c] bf16
    __shared__ unsigned short s_h1[8 * 64 * 32 + 32]; // [patch][pix][ch] + zero row
    constexpr int ZOFF = 8 * 64 * 32;

    const int tid = threadIdx.x;
    // zero h1 (incl. zero row): 16416 shorts = 8208 uints
    for (int d = tid; d < 8208; d += 256) ((unsigned int*)s_h1)[d] = 0u;
    for (int d = tid; d < 360; d += 256) {
        int o = d % 20, ct = d / 20, c = ct / 9, tap = ct % 9;
        s_w1[d] = w1[o * 18 + c * 9 + tap];   // s_w1[(c*9+tap)*20+o]
    }
    for (int d = tid; d < 4608; d += 256)
        ((unsigned int*)s_w2t)[d] = ((const unsigned int*)W2T)[d];
    if (tid < 20) s_b1[tid] = b1[tid];
    if (tid < 32) s_b2[tid] = (tid < 20) ? b2[tid] : 0.f;
    __syncthreads();

    // ---- conv1 (fp32 VALU): thread = (patch q, quarter: 2 px) ----
    const int q = tid >> 5, t = tid & 31;
    const int Pl = blockIdx.x * 8 + q;       // local row in chunk
    const int Pi = row0 + Pl;                // global patch index
    const bool valid = Pi < NPATCH;
    int b = 0, hi = 0, wi = 0;
    if (valid) { b = Pi / 2401; int rem = Pi - b * 2401; hi = rem / 49; wi = rem - hi * 49; }
    const int py = t >> 2, px0 = (t & 3) * 2;
    const float* ib = img + (long long)b * 21632 + (hi * 2) * 104 + (wi * 2);

    if (valid) {
        float acc1[2][20];
        #pragma unroll
        for (int j = 0; j < 2; ++j)
            #pragma unroll
            for (int o = 0; o < 20; ++o) acc1[j][o] = s_b1[o];

        #pragma unroll
        for (int c = 0; c < 2; ++c) {
            float win[3][4];
            #pragma unroll
            for (int dy = 0; dy < 3; ++dy) {
                int ny = py + dy - 1;
                int nyc = ny < 0 ? 0 : (ny > 7 ? 7 : ny);
                #pragma unroll
                for (int dxw = 0; dxw < 4; ++dxw) {
                    int nx = px0 + dxw - 1;
                    int nxc = nx < 0 ? 0 : (nx > 7 ? 7 : nx);
                    float v = ib[c * 10816 + nyc * 104 + nxc];   // clamped -> in-bounds
                    bool ok = (ny >= 0) && (ny < 8) && (nx >= 0) && (nx < 8);
                    win[dy][dxw] = ok ? v : 0.f;
                }
            }
            #pragma unroll
            for (int tap = 0; tap < 9; ++tap) {
                const int dy = tap / 3, dx = tap % 3;
                const float* wrow = &s_w1[(c * 9 + tap) * 20];
                #pragma unroll
                for (int o4 = 0; o4 < 5; ++o4) {
                    floatx4 wv = *(const floatx4*)&wrow[o4 * 4];
                    #pragma unroll
                    for (int j = 0; j < 2; ++j)
                        #pragma unroll
                        for (int oo = 0; oo < 4; ++oo)
                            acc1[j][o4 * 4 + oo] = fmaf(win[dy][dx + j], wv[oo], acc1[j][o4 * 4 + oo]);
                }
            }
        }
        // relu -> bf16 -> LDS [patch][pix][ch], ch pairs packed as uint
        #pragma unroll
        for (int j = 0; j < 2; ++j) {
            unsigned short* hrow = &s_h1[(q * 64 + py * 8 + px0 + j) * 32];
            #pragma unroll
            for (int o = 0; o < 20; o += 2) {
                unsigned int lo = f2b(fmaxf(acc1[j][o], 0.f));
                unsigned int hh = f2b(fmaxf(acc1[j][o + 1], 0.f));
                *(unsigned int*)&hrow[o] = lo | (hh << 16);
            }
        }
    }
    __syncthreads();

    // ---- conv2 (MFMA): wave owns patches p0, p0+1 ----
    const int wave = tid >> 6, lane = tid & 63;
    const int l15 = lane & 15, quad = lane >> 4;
    const int p0 = wave * 2;

    int pyv[4], pxv[4];
    #pragma unroll
    for (int mt = 0; mt < 4; ++mt) {
        int p = mt * 16 + l15;
        pyv[mt] = p >> 3; pxv[mt] = p & 7;
    }

    floatx4 acc[2][4][2] = {};

    #pragma unroll 1
    for (int dy = 0; dy < 3; ++dy) {
        // per-mt shifted-row offset (or -1 if row OOB)
        int rowoff[4]; bool okY[4];
        #pragma unroll
        for (int mt = 0; mt < 4; ++mt) {
            int sy = pyv[mt] + dy - 1;
            okY[mt] = (unsigned)sy < 8u;
            rowoff[mt] = sy * 256;              // (sy*8)*32 shorts
        }
        #pragma unroll
        for (int dx = 0; dx < 3; ++dx) {
            const int tap = dy * 3 + dx;
            short8 bf0 = *(const short8*)&s_w2t[(tap * 32 + l15) * 32 + quad * 8];
            short8 bf1 = *(const short8*)&s_w2t[(tap * 32 + 16 + l15) * 32 + quad * 8];
            #pragma unroll
            for (int pp = 0; pp < 2; ++pp) {
                const int pbase = (p0 + pp) * 2048;
                #pragma unroll
                for (int mt = 0; mt < 4; ++mt) {
                    int sx = pxv[mt] + dx - 1;
                    bool ok = okY[mt] & ((unsigned)sx < 8u);
                    int off = ok ? (pbase + rowoff[mt] + sx * 32) : ZOFF;
                    short8 af = *(const short8*)&s_h1[off + quad * 8];
                    acc[pp][mt][0] = __builtin_amdgcn_mfma_f32_16x16x32_bf16(af, bf0, acc[pp][mt][0], 0, 0, 0);
                    acc[pp][mt][1] = __builtin_amdgcn_mfma_f32_16x16x32_bf16(af, bf1, acc[pp][mt][1], 0, 0, 0);
                }
            }
        }
    }

    // ---- epilogue: bias + relu + bf16, X[Pl][o*64 + pix] ----
    #pragma unroll
    for (int pp = 0; pp < 2; ++pp) {
        unsigned short* xrow = X + (long long)(blockIdx.x * 8 + p0 + pp) * K1;
        #pragma unroll
        for (int nt = 0; nt < 2; ++nt) {
            const int col = nt * 16 + l15;
            if (col < 20) {
                const float bv = s_b2[col];
                #pragma unroll
                for (int mt = 0; mt < 4; ++mt) {
                    unsigned short r4[4];
                    #pragma unroll
                    for (int r = 0; r < 4; ++r)
                        r4[r] = f2b(fmaxf(acc[pp][mt][nt][r] + bv, 0.f));
                    unsigned int w0 = (unsigned int)r4[0] | ((unsigned int)r4[1] << 16);
                    unsigned int w1v = (unsigned int)r4[2] | ((unsigned int)r4[3] << 16);
                    unsigned int* dst = (unsigned int*)&xrow[col * 64 + mt * 16 + quad * 4];
                    dst[0] = w0; dst[1] = w1v;
                }
            }
        }
    }
}

// ---------- bf16 MFMA GEMM: C[rows][256] = relu(A[rows][K] @ W[256][K]^T + bias) ----------
template<int K, bool RELU>
__global__ __launch_bounds__(256, 2) void gemm_bt(
    const unsigned short* __restrict__ A,
    const unsigned short* __restrict__ W,
    const float* __restrict__ bias,
    unsigned short* __restrict__ C)
{
    constexpr int BK = 64;
    constexpr int LDR = BK + 8;   // +16B pad
    __shared__ unsigned short s_a[128 * LDR];
    __shared__ unsigned short s_b[128 * LDR];

    const int tid = threadIdx.x;
    const int m0 = blockIdx.x * 128, n0 = blockIdx.y * 128;
    const int wave = tid >> 6, lane = tid & 63;
    const int wm = wave >> 1, wn = wave & 1;
    const int l15 = lane & 15, quad = lane >> 4;

    floatx4 acc[4][4] = {};

    #pragma unroll 1
    for (int kt = 0; kt < K; kt += BK) {
        #pragma unroll
        for (int i = 0; i < 4; ++i) {
            int chunk = tid + i * 256;            // 0..1023
            int row = chunk >> 3, kv = (chunk & 7) * 8;
            *(uint4*)&s_a[row * LDR + kv] = *(const uint4*)(A + (long long)(m0 + row) * K + kt + kv);
            *(uint4*)&s_b[row * LDR + kv] = *(const uint4*)(W + (long long)(n0 + row) * K + kt + kv);
        }
        __syncthreads();
        #pragma unroll
        for (int kh = 0; kh < 2; ++kh) {
            const int kk = kh * 32;
            short8 af[4], bf[4];
            #pragma unroll
            for (int mt = 0; mt < 4; ++mt)
                af[mt] = *(const short8*)&s_a[(wm * 64 + mt * 16 + l15) * LDR + kk + quad * 8];
            #pragma unroll
            for (int nt = 0; nt < 4; ++nt)
                bf[nt] = *(const short8*)&s_b[(wn * 64 + nt * 16 + l15) * LDR + kk + quad * 8];
            #pragma unroll
            for (int mt = 0; mt < 4; ++mt)
                #pragma unroll
                for (int nt = 0; nt < 4; ++nt)
                    acc[mt][nt] = __builtin_amdgcn_mfma_f32_16x16x32_bf16(af[mt], bf[nt], acc[mt][nt], 0, 0, 0);
        }
        __syncthreads();
    }

    #pragma unroll
    for (int nt = 0; nt < 4; ++nt) {
        const int col = n0 + wn * 64 + nt * 16 + l15;
        const float bv = bias[col];
        #pragma unroll
        for (int mt = 0; mt < 4; ++mt) {
            #pragma unroll
            for (int r = 0; r < 4; ++r) {
                int row = m0 + wm * 64 + mt * 16 + quad * 4 + r;
                float v = acc[mt][nt][r] + bv;
                if (RELU) v = fmaxf(v, 0.f);
                C[(long long)row * 256 + col] = f2b(v);
            }
        }
    }
}

// ---------- final layer: out[global rows][27] = H[.][256] @ W[27][256]^T + b (fp32) ----------
__global__ __launch_bounds__(256, 2) void fcf_kernel(
    const unsigned short* __restrict__ H,
    const float* __restrict__ W,
    const float* __restrict__ B,
    float* __restrict__ out, int row0)
{
    constexpr int LDW = 260;
    __shared__ float s_w[27 * LDW];
    __shared__ float s_bb[32];
    __shared__ unsigned short s_h[8 * 256];

    const int tid = threadIdx.x;
    for (int d = tid; d < 27 * 256; d += 256) {
        int o = d >> 8, k = d & 255;
        s_w[o * LDW + k] = W[d];
    }
    if (tid < 27) s_bb[tid] = B[tid];
    const int rl0 = blockIdx.x * 8;     // local row base in chunk
    {
        int r = tid >> 5, k8 = (tid & 31) * 8;
        *(uint4*)&s_h[r * 256 + k8] = *(const uint4*)&H[(long long)(rl0 + r) * 256 + k8];
    }
    __syncthreads();

    const int r = tid >> 5, o = tid & 31;
    const int grow = row0 + rl0 + r;
    if (o < 27 && grow < NPATCH) {
        float acc = s_bb[o];
        const unsigned short* hp = &s_h[r * 256];
        const float* wp = &s_w[o * LDW];
        #pragma unroll 4
        for (int k = 0; k < 256; k += 8) {
            short8 hv = *(const short8*)&hp[k];
            floatx4 w0 = *(const floatx4*)&wp[k];
            floatx4 w1 = *(const floatx4*)&wp[k + 4];
            acc = fmaf(b2f((unsigned short)hv[0]), w0[0], acc);
            acc = fmaf(b2f((unsigned short)hv[1]), w0[1], acc);
            acc = fmaf(b2f((unsigned short)hv[2]), w0[2], acc);
            acc = fmaf(b2f((unsigned short)hv[3]), w0[3], acc);
            acc = fmaf(b2f((unsigned short)hv[4]), w1[0], acc);
            acc = fmaf(b2f((unsigned short)hv[5]), w1[1], acc);
            acc = fmaf(b2f((unsigned short)hv[6]), w1[2], acc);
            acc = fmaf(b2f((unsigned short)hv[7]), w1[3], acc);
        }
        out[(long long)grow * 27 + o] = acc;
    }
}

extern "C" void kernel_launch(void* const* d_in, const int* in_sizes, int n_in,
                              void* d_out, int out_size, void* d_ws, size_t ws_size,
                              hipStream_t stream) {
    const float* images = (const float*)d_in[0];
    const float* c1w = (const float*)d_in[1];
    const float* c1b = (const float*)d_in[2];
    const float* c2w = (const float*)d_in[3];
    const float* c2b = (const float*)d_in[4];
    const float* f1w = (const float*)d_in[5];
    const float* f1b = (const float*)d_in[6];
    const float* f2w = (const float*)d_in[7];
    const float* f2b_ = (const float*)d_in[8];
    const float* f3w = (const float*)d_in[9];
    const float* f3b = (const float*)d_in[10];
    const float* ffw = (const float*)d_in[11];
    const float* ffb = (const float*)d_in[12];

    // ---- ws layout: [W1][W2][W3 bf16][W2T][X chunk][H1 chunk][H2 chunk] ----
    const long long W1_E = 256LL * 1280, W2_E = 256LL * 256, W3_E = 256LL * 256;
    const long long W2T_E = 9LL * 32 * 32;                  // 9216
    const long long WB = (W1_E + W2_E + W3_E) * 2 + W2T_E * 2;  // 935936 (256-aligned)
    char* ws = (char*)d_ws;
    unsigned short* W1  = (unsigned short*)ws;
    unsigned short* W2  = W1 + W1_E;
    unsigned short* W3  = W2 + W2_E;
    unsigned short* W2T = W3 + W3_E;

    // per 128-row block: X 128*1280*2 + H1 128*256*2 + H2 128*256*2 = 458752 B
    long long avail = (long long)ws_size - WB - 256;
    int nb_max = (int)(avail / 458752LL);
    if (nb_max < 1) nb_max = 1;
    if (nb_max > NBLK) nb_max = NBLK;

    unsigned short* X  = (unsigned short*)(ws + WB);
    unsigned short* H1 = X  + (long long)nb_max * 128 * K1;
    unsigned short* H2 = H1 + (long long)nb_max * 128 * NH;

    to_bf16<<<(int)((W1_E + 255) / 256), 256, 0, stream>>>(f1w, W1, (int)W1_E);
    to_bf16<<<(int)((W2_E + 255) / 256), 256, 0, stream>>>(f2w, W2, (int)W2_E);
    to_bf16<<<(int)((W3_E + 255) / 256), 256, 0, stream>>>(f3w, W3, (int)W3_E);
    to_w2t<<<36, 256, 0, stream>>>(c2w, W2T);

    for (int b0 = 0; b0 < NBLK; b0 += nb_max) {
        int nb = NBLK - b0; if (nb > nb_max) nb = nb_max;
        int row0 = b0 * 128;
        int rows = nb * 128;

        conv_mfma<<<rows / 8, 256, 0, stream>>>(images, c1w, c1b, W2T, c2b, X, row0);

        gemm_bt<1280, true><<<dim3(nb, 2), 256, 0, stream>>>(X,  W1, f1b, H1);
        gemm_bt<256,  true><<<dim3(nb, 2), 256, 0, stream>>>(H1, W2, f2b_, H2);
        gemm_bt<256,  true><<<dim3(nb, 2), 256, 0, stream>>>(H2, W3, f3b, H1);  // H1 reused for h3

        fcf_kernel<<<rows / 8, 256, 0, stream>>>(H1, ffw, ffb, (float*)d_out, row0);
    }
}

// Round 4
// 469.726 us; speedup vs baseline: 1.7233x; 1.1889x over previous
//
#include <hip/hip_runtime.h>

// ---------- constants ----------
#define NPATCH 76832   // 32 * 49 * 49
#define NBLK   601     // ceil(NPATCH/128)
#define K1     1280    // 20*8*8
#define NH     256

typedef __attribute__((ext_vector_type(8))) short  short8;
typedef __attribute__((ext_vector_type(4))) float  floatx4;

__device__ __forceinline__ unsigned short f2b(float f) {
    unsigned int u = __builtin_bit_cast(unsigned int, f);
    u += 0x7FFFu + ((u >> 16) & 1u);   // RNE
    return (unsigned short)(u >> 16);
}
__device__ __forceinline__ float b2f(unsigned short h) {
    unsigned int u = ((unsigned int)h) << 16;
    return __builtin_bit_cast(float, u);
}

// swizzled chunk index within a 128B pixel-pair window:
// row (pixel or o-row), chunk i in 0..3 -> position 0..7
__device__ __host__ __forceinline__ int swz8(int row, int i) {
    return (((row & 1) * 4 + i) ^ ((row >> 1) & 7));
}

// ---------- weight fp32 -> bf16 ----------
__global__ void to_bf16(const float* __restrict__ src, unsigned short* __restrict__ dst, int n) {
    int i = blockIdx.x * 256 + threadIdx.x;
    if (i < n) dst[i] = f2b(src[i]);
}

// ---------- conv1 weights -> W1T[o:32][k:32] bf16, swizzled ----------
__global__ void to_w1t(const float* __restrict__ w1, unsigned short* __restrict__ dst) {
    int i = blockIdx.x * 256 + threadIdx.x;
    if (i >= 32 * 32) return;
    int o = i >> 5, k = i & 31;
    unsigned short v = 0;
    if (o < 20 && k < 18) v = f2b(w1[o * 18 + k]);   // k = c*9 + tap, row-major [o][c][3][3]
    dst[(o >> 1) * 64 + swz8(o, k >> 3) * 8 + (k & 7)] = v;
}

// ---------- conv2 weights -> W2T[tap][o:32][c:32] bf16, swizzled ----------
__global__ void to_w2t(const float* __restrict__ w2, unsigned short* __restrict__ dst) {
    int i = blockIdx.x * 256 + threadIdx.x;
    if (i >= 9 * 32 * 32) return;
    int tap = i >> 10, rem = i & 1023, o = rem >> 5, c = rem & 31;
    unsigned short v = 0;
    if (o < 20 && c < 20) v = f2b(w2[o * 180 + c * 9 + tap]);
    dst[tap * 1024 + (o >> 1) * 64 + swz8(o, c >> 3) * 8 + (c & 7)] = v;
}

// ---------- fused tile + conv1(MFMA) + conv2(MFMA) ----------
// 256 threads = 8 patches/block. Gather: 32 thr/patch, 2 px each.
// MFMA: wave w owns patches {2w, 2w+1}.
__global__ __launch_bounds__(256, 2) void conv_mfma(
    const float* __restrict__ img,
    const unsigned short* __restrict__ W1T, const float* __restrict__ b1,
    const unsigned short* __restrict__ W2T, const float* __restrict__ b2,
    unsigned short* __restrict__ X, int row0)
{
    __shared__ alignas(16) unsigned short s_buf[8 * 2048 + 64];  // A1 then h1; + 128B zero chunk
    __shared__ alignas(16) unsigned short s_w1t[1024];
    __shared__ alignas(16) unsigned short s_w2t[9216];
    __shared__ float s_b1[32], s_b2[32];
    constexpr int ZOFF = 8 * 2048;

    const int tid = threadIdx.x;
    for (int d = tid; d < 512; d += 256)  ((unsigned int*)s_w1t)[d] = ((const unsigned int*)W1T)[d];
    for (int d = tid; d < 4608; d += 256) ((unsigned int*)s_w2t)[d] = ((const unsigned int*)W2T)[d];
    if (tid < 32) {
        ((unsigned int*)&s_buf[ZOFF])[tid] = 0u;
        s_b1[tid] = (tid < 20) ? b1[tid] : 0.f;
        s_b2[tid] = (tid < 20) ? b2[tid] : 0.f;
    }

    // ---- gather: build A1[pix][k=c*9+tap] (bf16, masked zero-pad), swizzled ----
    const int q = tid >> 5, t = tid & 31;
    const int Pl = blockIdx.x * 8 + q;       // local row in chunk
    const int Pi = row0 + Pl;                // global patch index
    const bool valid = Pi < NPATCH;
    int b = 0, hi = 0, wi = 0;
    if (valid) { b = Pi / 2401; int rem = Pi - b * 2401; hi = rem / 49; wi = rem - hi * 49; }
    const int py = t >> 2, px0 = (t & 3) * 2;
    const float* ib = img + (long long)b * 21632 + (hi * 2) * 104 + (wi * 2);

    float win[2][3][4];
    #pragma unroll
    for (int c = 0; c < 2; ++c)
        #pragma unroll
        for (int dy = 0; dy < 3; ++dy) {
            int ny = py + dy - 1;
            int nyc = ny < 0 ? 0 : (ny > 7 ? 7 : ny);
            #pragma unroll
            for (int dxw = 0; dxw < 4; ++dxw) {
                int nx = px0 + dxw - 1;
                int nxc = nx < 0 ? 0 : (nx > 7 ? 7 : nx);
                win[c][dy][dxw] = ib[c * 10816 + nyc * 104 + nxc];   // clamped -> in-bounds
            }
        }

    #pragma unroll
    for (int j = 0; j < 2; ++j) {
        const int px = px0 + j, pl = py * 8 + px;
        alignas(16) unsigned short a[32];
        #pragma unroll
        for (int k = 18; k < 32; ++k) a[k] = 0;
        #pragma unroll
        for (int c = 0; c < 2; ++c)
            #pragma unroll
            for (int dy = 0; dy < 3; ++dy) {
                int ny = py + dy - 1;
                bool rok = valid && ((unsigned)ny < 8u);
                #pragma unroll
                for (int dx = 0; dx < 3; ++dx) {
                    int nx = px + dx - 1;
                    bool ok = rok && ((unsigned)nx < 8u);
                    a[c * 9 + dy * 3 + dx] = f2b(ok ? win[c][dy][dx + j] : 0.f);
                }
            }
        unsigned short* base = &s_buf[q * 2048 + (pl >> 1) * 64];
        #pragma unroll
        for (int i = 0; i < 4; ++i)
            *(uint4*)&base[swz8(pl, i) * 8] = *(const uint4*)&a[i * 8];
    }
    __syncthreads();

    // ---- conv1 MFMA ----
    const int wave = tid >> 6, lane = tid & 63;
    const int l15 = lane & 15, quad = lane >> 4;
    const int p0 = wave * 2;

    int boffW[2];
    #pragma unroll
    for (int nt = 0; nt < 2; ++nt) {
        int oo = nt * 16 + l15;
        boffW[nt] = (oo >> 1) * 64 + swz8(oo, quad) * 8;
    }

    floatx4 acc1[2][4][2] = {};
    #pragma unroll
    for (int pp = 0; pp < 2; ++pp)
        #pragma unroll
        for (int mt = 0; mt < 4; ++mt) {
            int p = mt * 16 + l15;
            short8 af = *(const short8*)&s_buf[(p0 + pp) * 2048 + (p >> 1) * 64 + swz8(p, quad) * 8];
            short8 b0 = *(const short8*)&s_w1t[boffW[0]];
            short8 b1f = *(const short8*)&s_w1t[boffW[1]];
            acc1[pp][mt][0] = __builtin_amdgcn_mfma_f32_16x16x32_bf16(af, b0,  acc1[pp][mt][0], 0, 0, 0);
            acc1[pp][mt][1] = __builtin_amdgcn_mfma_f32_16x16x32_bf16(af, b1f, acc1[pp][mt][1], 0, 0, 0);
        }
    __syncthreads();

    // ---- h1 = relu(conv1 + b1) -> overwrite s_buf, layout [patch][pix][32ch] swizzled ----
    #pragma unroll
    for (int pp = 0; pp < 2; ++pp)
        #pragma unroll
        for (int nt = 0; nt < 2; ++nt) {
            const int o = nt * 16 + l15;
            const float bv = s_b1[o];
            #pragma unroll
            for (int mt = 0; mt < 4; ++mt)
                #pragma unroll
                for (int r = 0; r < 4; ++r) {
                    int p = mt * 16 + quad * 4 + r;
                    unsigned short hv = f2b(fmaxf(acc1[pp][mt][nt][r] + bv, 0.f));  // o>=20: acc=0,bv=0 -> 0
                    s_buf[(p0 + pp) * 2048 + (p >> 1) * 64 + swz8(p, o >> 3) * 8 + (o & 7)] = hv;
                }
        }
    __syncthreads();

    // ---- conv2 MFMA (tap loop) ----
    int syv[4], pxv[4];
    #pragma unroll
    for (int mt = 0; mt < 4; ++mt) { int p = mt * 16 + l15; syv[mt] = p >> 3; pxv[mt] = p & 7; }

    floatx4 acc2[2][4][2] = {};
    #pragma unroll 1
    for (int dy = 0; dy < 3; ++dy) {
        int sy[4]; bool okY[4];
        #pragma unroll
        for (int mt = 0; mt < 4; ++mt) {
            sy[mt] = syv[mt] + dy - 1;
            okY[mt] = (unsigned)sy[mt] < 8u;
        }
        #pragma unroll
        for (int dx = 0; dx < 3; ++dx) {
            const int tap = dy * 3 + dx;
            short8 bf0 = *(const short8*)&s_w2t[tap * 1024 + boffW[0]];
            short8 bf1 = *(const short8*)&s_w2t[tap * 1024 + boffW[1]];
            #pragma unroll
            for (int mt = 0; mt < 4; ++mt) {
                int sx = pxv[mt] + dx - 1;
                bool ok = okY[mt] & ((unsigned)sx < 8u);
                int ps = sy[mt] * 8 + sx;
                int offl = (ps >> 1) * 64 + swz8(ps, quad) * 8;
                #pragma unroll
                for (int pp = 0; pp < 2; ++pp) {
                    int off = ok ? ((p0 + pp) * 2048 + offl) : (ZOFF + quad * 8);
                    short8 af = *(const short8*)&s_buf[off];
                    acc2[pp][mt][0] = __builtin_amdgcn_mfma_f32_16x16x32_bf16(af, bf0, acc2[pp][mt][0], 0, 0, 0);
                    acc2[pp][mt][1] = __builtin_amdgcn_mfma_f32_16x16x32_bf16(af, bf1, acc2[pp][mt][1], 0, 0, 0);
                }
            }
        }
    }

    // ---- epilogue: bias + relu + bf16, X[Pl][o*64 + pix] ----
    #pragma unroll
    for (int pp = 0; pp < 2; ++pp) {
        unsigned short* xrow = X + (long long)(blockIdx.x * 8 + p0 + pp) * K1;
        #pragma unroll
        for (int nt = 0; nt < 2; ++nt) {
            const int col = nt * 16 + l15;
            if (col < 20) {
                const float bv = s_b2[col];
                #pragma unroll
                for (int mt = 0; mt < 4; ++mt) {
                    unsigned short r4[4];
                    #pragma unroll
                    for (int r = 0; r < 4; ++r)
                        r4[r] = f2b(fmaxf(acc2[pp][mt][nt][r] + bv, 0.f));
                    unsigned int w0 = (unsigned int)r4[0] | ((unsigned int)r4[1] << 16);
                    unsigned int w1v = (unsigned int)r4[2] | ((unsigned int)r4[3] << 16);
                    unsigned int* dst = (unsigned int*)&xrow[col * 64 + mt * 16 + quad * 4];
                    dst[0] = w0; dst[1] = w1v;
                }
            }
        }
    }
}

// ---------- bf16 MFMA GEMM: C[rows][256] = relu(A[rows][K] @ W[256][K]^T + bias) ----------
template<int K, bool RELU>
__global__ __launch_bounds__(256, 2) void gemm_bt(
    const unsigned short* __restrict__ A,
    const unsigned short* __restrict__ W,
    const float* __restrict__ bias,
    unsigned short* __restrict__ C)
{
    constexpr int BK = 64;
    constexpr int LDR = BK + 8;   // +16B pad
    __shared__ unsigned short s_a[128 * LDR];
    __shared__ unsigned short s_b[128 * LDR];

    const int tid = threadIdx.x;
    const int m0 = blockIdx.x * 128, n0 = blockIdx.y * 128;
    const int wave = tid >> 6, lane = tid & 63;
    const int wm = wave >> 1, wn = wave & 1;
    const int l15 = lane & 15, quad = lane >> 4;

    floatx4 acc[4][4] = {};

    #pragma unroll 1
    for (int kt = 0; kt < K; kt += BK) {
        #pragma unroll
        for (int i = 0; i < 4; ++i) {
            int chunk = tid + i * 256;            // 0..1023
            int row = chunk >> 3, kv = (chunk & 7) * 8;
            *(uint4*)&s_a[row * LDR + kv] = *(const uint4*)(A + (long long)(m0 + row) * K + kt + kv);
            *(uint4*)&s_b[row * LDR + kv] = *(const uint4*)(W + (long long)(n0 + row) * K + kt + kv);
        }
        __syncthreads();
        #pragma unroll
        for (int kh = 0; kh < 2; ++kh) {
            const int kk = kh * 32;
            short8 af[4], bf[4];
            #pragma unroll
            for (int mt = 0; mt < 4; ++mt)
                af[mt] = *(const short8*)&s_a[(wm * 64 + mt * 16 + l15) * LDR + kk + quad * 8];
            #pragma unroll
            for (int nt = 0; nt < 4; ++nt)
                bf[nt] = *(const short8*)&s_b[(wn * 64 + nt * 16 + l15) * LDR + kk + quad * 8];
            #pragma unroll
            for (int mt = 0; mt < 4; ++mt)
                #pragma unroll
                for (int nt = 0; nt < 4; ++nt)
                    acc[mt][nt] = __builtin_amdgcn_mfma_f32_16x16x32_bf16(af[mt], bf[nt], acc[mt][nt], 0, 0, 0);
        }
        __syncthreads();
    }

    #pragma unroll
    for (int nt = 0; nt < 4; ++nt) {
        const int col = n0 + wn * 64 + nt * 16 + l15;
        const float bv = bias[col];
        #pragma unroll
        for (int mt = 0; mt < 4; ++mt) {
            #pragma unroll
            for (int r = 0; r < 4; ++r) {
                int row = m0 + wm * 64 + mt * 16 + quad * 4 + r;
                float v = acc[mt][nt][r] + bv;
                if (RELU) v = fmaxf(v, 0.f);
                C[(long long)row * 256 + col] = f2b(v);
            }
        }
    }
}

// ---------- final layer: out[global rows][27] = H[.][256] @ W[27][256]^T + b (fp32) ----------
__global__ __launch_bounds__(256, 2) void fcf_kernel(
    const unsigned short* __restrict__ H,
    const float* __restrict__ W,
    const float* __restrict__ B,
    float* __restrict__ out, int row0)
{
    constexpr int LDW = 260;
    __shared__ float s_w[27 * LDW];
    __shared__ float s_bb[32];
    __shared__ unsigned short s_h[8 * 256];

    const int tid = threadIdx.x;
    for (int d = tid; d < 27 * 256; d += 256) {
        int o = d >> 8, k = d & 255;
        s_w[o * LDW + k] = W[d];
    }
    if (tid < 27) s_bb[tid] = B[tid];
    const int rl0 = blockIdx.x * 8;     // local row base in chunk
    {
        int r = tid >> 5, k8 = (tid & 31) * 8;
        *(uint4*)&s_h[r * 256 + k8] = *(const uint4*)&H[(long long)(rl0 + r) * 256 + k8];
    }
    __syncthreads();

    const int r = tid >> 5, o = tid & 31;
    const int grow = row0 + rl0 + r;
    if (o < 27 && grow < NPATCH) {
        float acc = s_bb[o];
        const unsigned short* hp = &s_h[r * 256];
        const float* wp = &s_w[o * LDW];
        #pragma unroll 4
        for (int k = 0; k < 256; k += 8) {
            short8 hv = *(const short8*)&hp[k];
            floatx4 w0 = *(const floatx4*)&wp[k];
            floatx4 w1 = *(const floatx4*)&wp[k + 4];
            acc = fmaf(b2f((unsigned short)hv[0]), w0[0], acc);
            acc = fmaf(b2f((unsigned short)hv[1]), w0[1], acc);
            acc = fmaf(b2f((unsigned short)hv[2]), w0[2], acc);
            acc = fmaf(b2f((unsigned short)hv[3]), w0[3], acc);
            acc = fmaf(b2f((unsigned short)hv[4]), w1[0], acc);
            acc = fmaf(b2f((unsigned short)hv[5]), w1[1], acc);
            acc = fmaf(b2f((unsigned short)hv[6]), w1[2], acc);
            acc = fmaf(b2f((unsigned short)hv[7]), w1[3], acc);
        }
        out[(long long)grow * 27 + o] = acc;
    }
}

extern "C" void kernel_launch(void* const* d_in, const int* in_sizes, int n_in,
                              void* d_out, int out_size, void* d_ws, size_t ws_size,
                              hipStream_t stream) {
    const float* images = (const float*)d_in[0];
    const float* c1w = (const float*)d_in[1];
    const float* c1b = (const float*)d_in[2];
    const float* c2w = (const float*)d_in[3];
    const float* c2b = (const float*)d_in[4];
    const float* f1w = (const float*)d_in[5];
    const float* f1b = (const float*)d_in[6];
    const float* f2w = (const float*)d_in[7];
    const float* f2b_ = (const float*)d_in[8];
    const float* f3w = (const float*)d_in[9];
    const float* f3b = (const float*)d_in[10];
    const float* ffw = (const float*)d_in[11];
    const float* ffb = (const float*)d_in[12];

    // ---- ws layout: [W1][W2][W3 bf16][W2T][W1T][X chunk][H1 chunk][H2 chunk] ----
    const long long W1_E = 256LL * 1280, W2_E = 256LL * 256, W3_E = 256LL * 256;
    const long long W2T_E = 9LL * 32 * 32, W1T_E = 32LL * 32;
    const long long WB = (W1_E + W2_E + W3_E + W2T_E + W1T_E) * 2;   // 937984
    char* ws = (char*)d_ws;
    unsigned short* W1  = (unsigned short*)ws;
    unsigned short* W2  = W1 + W1_E;
    unsigned short* W3  = W2 + W2_E;
    unsigned short* W2T = W3 + W3_E;
    unsigned short* W1T = W2T + W2T_E;

    // per 128-row block: X 128*1280*2 + H1 128*256*2 + H2 128*256*2 = 458752 B
    long long avail = (long long)ws_size - WB - 256;
    int nb_max = (int)(avail / 458752LL);
    if (nb_max < 1) nb_max = 1;
    if (nb_max > NBLK) nb_max = NBLK;

    unsigned short* X  = (unsigned short*)(ws + WB);
    unsigned short* H1 = X  + (long long)nb_max * 128 * K1;
    unsigned short* H2 = H1 + (long long)nb_max * 128 * NH;

    to_bf16<<<(int)((W1_E + 255) / 256), 256, 0, stream>>>(f1w, W1, (int)W1_E);
    to_bf16<<<(int)((W2_E + 255) / 256), 256, 0, stream>>>(f2w, W2, (int)W2_E);
    to_bf16<<<(int)((W3_E + 255) / 256), 256, 0, stream>>>(f3w, W3, (int)W3_E);
    to_w1t<<<4, 256, 0, stream>>>(c1w, W1T);
    to_w2t<<<36, 256, 0, stream>>>(c2w, W2T);

    for (int b0 = 0; b0 < NBLK; b0 += nb_max) {
        int nb = NBLK - b0; if (nb > nb_max) nb = nb_max;
        int row0 = b0 * 128;
        int rows = nb * 128;

        conv_mfma<<<rows / 8, 256, 0, stream>>>(images, W1T, c1b, W2T, c2b, X, row0);

        gemm_bt<1280, true><<<dim3(nb, 2), 256, 0, stream>>>(X,  W1, f1b, H1);
        gemm_bt<256,  true><<<dim3(nb, 2), 256, 0, stream>>>(H1, W2, f2b_, H2);
        gemm_bt<256,  true><<<dim3(nb, 2), 256, 0, stream>>>(H2, W3, f3b, H1);  // H1 reused for h3

        fcf_kernel<<<rows / 8, 256, 0, stream>>>(H1, ffw, ffb, (float*)d_out, row0);
    }
}

// Round 5
// 447.384 us; speedup vs baseline: 1.8094x; 1.0499x over previous
//
#include <hip/hip_runtime.h>

// ---------- constants ----------
#define NPATCH 76832   // 32 * 49 * 49
#define NBLK   601     // ceil(NPATCH/128)
#define K1     1280    // 20*8*8
#define NH     256

typedef __attribute__((ext_vector_type(8))) short  short8;
typedef __attribute__((ext_vector_type(4))) float  floatx4;

__device__ __forceinline__ unsigned short f2b(float f) {
    unsigned int u = __builtin_bit_cast(unsigned int, f);
    u += 0x7FFFu + ((u >> 16) & 1u);   // RNE
    return (unsigned short)(u >> 16);
}
__device__ __forceinline__ float b2f(unsigned short h) {
    unsigned int u = ((unsigned int)h) << 16;
    return __builtin_bit_cast(float, u);
}

// async global->LDS, 16B per lane; lds dest = wave-uniform base + lane*16
__device__ __forceinline__ void gload_lds16(const unsigned short* g, unsigned short* l) {
    __builtin_amdgcn_global_load_lds(
        (__attribute__((address_space(1))) void*)g,
        (__attribute__((address_space(3))) void*)l,
        16, 0, 0);
}

// swizzled chunk index within a 128B pixel-pair window
__device__ __host__ __forceinline__ int swz8(int row, int i) {
    return (((row & 1) * 4 + i) ^ ((row >> 1) & 7));
}

// ---------- weight fp32 -> bf16 ----------
__global__ void to_bf16(const float* __restrict__ src, unsigned short* __restrict__ dst, int n) {
    int i = blockIdx.x * 256 + threadIdx.x;
    if (i < n) dst[i] = f2b(src[i]);
}

// ---------- conv1 weights -> W1T[o:32][k:32] bf16, swizzled ----------
__global__ void to_w1t(const float* __restrict__ w1, unsigned short* __restrict__ dst) {
    int i = blockIdx.x * 256 + threadIdx.x;
    if (i >= 32 * 32) return;
    int o = i >> 5, k = i & 31;
    unsigned short v = 0;
    if (o < 20 && k < 18) v = f2b(w1[o * 18 + k]);   // k = c*9 + tap
    dst[(o >> 1) * 64 + swz8(o, k >> 3) * 8 + (k & 7)] = v;
}

// ---------- conv2 weights -> W2T[tap][o:32][c:32] bf16, swizzled ----------
__global__ void to_w2t(const float* __restrict__ w2, unsigned short* __restrict__ dst) {
    int i = blockIdx.x * 256 + threadIdx.x;
    if (i >= 9 * 32 * 32) return;
    int tap = i >> 10, rem = i & 1023, o = rem >> 5, c = rem & 31;
    unsigned short v = 0;
    if (o < 20 && c < 20) v = f2b(w2[o * 180 + c * 9 + tap]);
    dst[tap * 1024 + (o >> 1) * 64 + swz8(o, c >> 3) * 8 + (c & 7)] = v;
}

// ---------- fused tile + conv1(MFMA) + conv2(MFMA) ----------
__global__ __launch_bounds__(256, 2) void conv_mfma(
    const float* __restrict__ img,
    const unsigned short* __restrict__ W1T, const float* __restrict__ b1,
    const unsigned short* __restrict__ W2T, const float* __restrict__ b2,
    unsigned short* __restrict__ X, int row0)
{
    __shared__ alignas(16) unsigned short s_buf[8 * 2048 + 64];
    __shared__ alignas(16) unsigned short s_w1t[1024];
    __shared__ alignas(16) unsigned short s_w2t[9216];
    __shared__ float s_b1[32], s_b2[32];
    constexpr int ZOFF = 8 * 2048;

    const int tid = threadIdx.x;
    for (int d = tid; d < 512; d += 256)  ((unsigned int*)s_w1t)[d] = ((const unsigned int*)W1T)[d];
    for (int d = tid; d < 4608; d += 256) ((unsigned int*)s_w2t)[d] = ((const unsigned int*)W2T)[d];
    if (tid < 32) {
        ((unsigned int*)&s_buf[ZOFF])[tid] = 0u;
        s_b1[tid] = (tid < 20) ? b1[tid] : 0.f;
        s_b2[tid] = (tid < 20) ? b2[tid] : 0.f;
    }

    const int q = tid >> 5, t = tid & 31;
    const int Pl = blockIdx.x * 8 + q;
    const int Pi = row0 + Pl;
    const bool valid = Pi < NPATCH;
    int b = 0, hi = 0, wi = 0;
    if (valid) { b = Pi / 2401; int rem = Pi - b * 2401; hi = rem / 49; wi = rem - hi * 49; }
    const int py = t >> 2, px0 = (t & 3) * 2;
    const float* ib = img + (long long)b * 21632 + (hi * 2) * 104 + (wi * 2);

    float win[2][3][4];
    #pragma unroll
    for (int c = 0; c < 2; ++c)
        #pragma unroll
        for (int dy = 0; dy < 3; ++dy) {
            int ny = py + dy - 1;
            int nyc = ny < 0 ? 0 : (ny > 7 ? 7 : ny);
            #pragma unroll
            for (int dxw = 0; dxw < 4; ++dxw) {
                int nx = px0 + dxw - 1;
                int nxc = nx < 0 ? 0 : (nx > 7 ? 7 : nx);
                win[c][dy][dxw] = ib[c * 10816 + nyc * 104 + nxc];
            }
        }

    #pragma unroll
    for (int j = 0; j < 2; ++j) {
        const int px = px0 + j, pl = py * 8 + px;
        alignas(16) unsigned short a[32];
        #pragma unroll
        for (int k = 18; k < 32; ++k) a[k] = 0;
        #pragma unroll
        for (int c = 0; c < 2; ++c)
            #pragma unroll
            for (int dy = 0; dy < 3; ++dy) {
                int ny = py + dy - 1;
                bool rok = valid && ((unsigned)ny < 8u);
                #pragma unroll
                for (int dx = 0; dx < 3; ++dx) {
                    int nx = px + dx - 1;
                    bool ok = rok && ((unsigned)nx < 8u);
                    a[c * 9 + dy * 3 + dx] = f2b(ok ? win[c][dy][dx + j] : 0.f);
                }
            }
        unsigned short* base = &s_buf[q * 2048 + (pl >> 1) * 64];
        #pragma unroll
        for (int i = 0; i < 4; ++i)
            *(uint4*)&base[swz8(pl, i) * 8] = *(const uint4*)&a[i * 8];
    }
    __syncthreads();

    const int wave = tid >> 6, lane = tid & 63;
    const int l15 = lane & 15, quad = lane >> 4;
    const int p0 = wave * 2;

    int boffW[2];
    #pragma unroll
    for (int nt = 0; nt < 2; ++nt) {
        int oo = nt * 16 + l15;
        boffW[nt] = (oo >> 1) * 64 + swz8(oo, quad) * 8;
    }

    floatx4 acc1[2][4][2] = {};
    #pragma unroll
    for (int pp = 0; pp < 2; ++pp)
        #pragma unroll
        for (int mt = 0; mt < 4; ++mt) {
            int p = mt * 16 + l15;
            short8 af = *(const short8*)&s_buf[(p0 + pp) * 2048 + (p >> 1) * 64 + swz8(p, quad) * 8];
            short8 b0 = *(const short8*)&s_w1t[boffW[0]];
            short8 b1f = *(const short8*)&s_w1t[boffW[1]];
            acc1[pp][mt][0] = __builtin_amdgcn_mfma_f32_16x16x32_bf16(af, b0,  acc1[pp][mt][0], 0, 0, 0);
            acc1[pp][mt][1] = __builtin_amdgcn_mfma_f32_16x16x32_bf16(af, b1f, acc1[pp][mt][1], 0, 0, 0);
        }
    __syncthreads();

    #pragma unroll
    for (int pp = 0; pp < 2; ++pp)
        #pragma unroll
        for (int nt = 0; nt < 2; ++nt) {
            const int o = nt * 16 + l15;
            const float bv = s_b1[o];
            #pragma unroll
            for (int mt = 0; mt < 4; ++mt)
                #pragma unroll
                for (int r = 0; r < 4; ++r) {
                    int p = mt * 16 + quad * 4 + r;
                    unsigned short hv = f2b(fmaxf(acc1[pp][mt][nt][r] + bv, 0.f));
                    s_buf[(p0 + pp) * 2048 + (p >> 1) * 64 + swz8(p, o >> 3) * 8 + (o & 7)] = hv;
                }
        }
    __syncthreads();

    int syv[4], pxv[4];
    #pragma unroll
    for (int mt = 0; mt < 4; ++mt) { int p = mt * 16 + l15; syv[mt] = p >> 3; pxv[mt] = p & 7; }

    floatx4 acc2[2][4][2] = {};
    #pragma unroll 1
    for (int dy = 0; dy < 3; ++dy) {
        int sy[4]; bool okY[4];
        #pragma unroll
        for (int mt = 0; mt < 4; ++mt) {
            sy[mt] = syv[mt] + dy - 1;
            okY[mt] = (unsigned)sy[mt] < 8u;
        }
        #pragma unroll
        for (int dx = 0; dx < 3; ++dx) {
            const int tap = dy * 3 + dx;
            short8 bf0 = *(const short8*)&s_w2t[tap * 1024 + boffW[0]];
            short8 bf1 = *(const short8*)&s_w2t[tap * 1024 + boffW[1]];
            #pragma unroll
            for (int mt = 0; mt < 4; ++mt) {
                int sx = pxv[mt] + dx - 1;
                bool ok = okY[mt] & ((unsigned)sx < 8u);
                int ps = sy[mt] * 8 + sx;
                int offl = (ps >> 1) * 64 + swz8(ps, quad) * 8;
                #pragma unroll
                for (int pp = 0; pp < 2; ++pp) {
                    int off = ok ? ((p0 + pp) * 2048 + offl) : (ZOFF + quad * 8);
                    short8 af = *(const short8*)&s_buf[off];
                    acc2[pp][mt][0] = __builtin_amdgcn_mfma_f32_16x16x32_bf16(af, bf0, acc2[pp][mt][0], 0, 0, 0);
                    acc2[pp][mt][1] = __builtin_amdgcn_mfma_f32_16x16x32_bf16(af, bf1, acc2[pp][mt][1], 0, 0, 0);
                }
            }
        }
    }

    #pragma unroll
    for (int pp = 0; pp < 2; ++pp) {
        unsigned short* xrow = X + (long long)(blockIdx.x * 8 + p0 + pp) * K1;
        #pragma unroll
        for (int nt = 0; nt < 2; ++nt) {
            const int col = nt * 16 + l15;
            if (col < 20) {
                const float bv = s_b2[col];
                #pragma unroll
                for (int mt = 0; mt < 4; ++mt) {
                    unsigned short r4[4];
                    #pragma unroll
                    for (int r = 0; r < 4; ++r)
                        r4[r] = f2b(fmaxf(acc2[pp][mt][nt][r] + bv, 0.f));
                    unsigned int w0 = (unsigned int)r4[0] | ((unsigned int)r4[1] << 16);
                    unsigned int w1v = (unsigned int)r4[2] | ((unsigned int)r4[3] << 16);
                    unsigned int* dst = (unsigned int*)&xrow[col * 64 + mt * 16 + quad * 4];
                    dst[0] = w0; dst[1] = w1v;
                }
            }
        }
    }
}

// ---------- full-N bf16 MFMA GEMM: C[rows][256] = relu(A[rows][K] @ W[256][K]^T + bias) ----------
// grid (nb,1); block = 128 rows x 256 cols; async LDS staging (unpadded, contiguous).
template<int K, bool RELU>
__global__ __launch_bounds__(256, 2) void gemm_full(
    const unsigned short* __restrict__ A,
    const unsigned short* __restrict__ W,
    const float* __restrict__ bias,
    unsigned short* __restrict__ C)
{
    constexpr int BK = 64;
    __shared__ alignas(16) unsigned short s_a[128 * BK];   // [row][64] raw
    __shared__ alignas(16) unsigned short s_b[256 * BK];   // [row][64] raw

    const int tid = threadIdx.x;
    const int m0 = blockIdx.x * 128;
    const int wave = tid >> 6, lane = tid & 63;
    const int wm = wave >> 1, wn = wave & 1;   // M-half(64) x N-half(128)
    const int l15 = lane & 15, quad = lane >> 4;
    const int srow = lane >> 3, scol = (lane & 7) * 8;

    floatx4 acc[4][8] = {};

    #pragma unroll 1
    for (int kt = 0; kt < K; kt += BK) {
        #pragma unroll
        for (int i = 0; i < 4; ++i) {
            int row = wave * 32 + i * 8 + srow;
            gload_lds16(A + (long long)(m0 + row) * K + kt + scol, &s_a[(wave * 4 + i) * 512]);
        }
        #pragma unroll
        for (int i = 0; i < 8; ++i) {
            int row = wave * 64 + i * 8 + srow;
            gload_lds16(W + (long long)row * K + kt + scol, &s_b[(wave * 8 + i) * 512]);
        }
        __syncthreads();
        #pragma unroll
        for (int kh = 0; kh < 2; ++kh) {
            const int kk = kh * 32;
            short8 af[4], bf[8];
            #pragma unroll
            for (int mt = 0; mt < 4; ++mt)
                af[mt] = *(const short8*)&s_a[(wm * 64 + mt * 16 + l15) * BK + kk + quad * 8];
            #pragma unroll
            for (int nt = 0; nt < 8; ++nt)
                bf[nt] = *(const short8*)&s_b[(wn * 128 + nt * 16 + l15) * BK + kk + quad * 8];
            #pragma unroll
            for (int mt = 0; mt < 4; ++mt)
                #pragma unroll
                for (int nt = 0; nt < 8; ++nt)
                    acc[mt][nt] = __builtin_amdgcn_mfma_f32_16x16x32_bf16(af[mt], bf[nt], acc[mt][nt], 0, 0, 0);
        }
        __syncthreads();
    }

    #pragma unroll
    for (int nt = 0; nt < 8; ++nt) {
        const int col = wn * 128 + nt * 16 + l15;
        const float bv = bias[col];
        #pragma unroll
        for (int mt = 0; mt < 4; ++mt) {
            #pragma unroll
            for (int r = 0; r < 4; ++r) {
                int row = m0 + wm * 64 + mt * 16 + quad * 4 + r;
                float v = acc[mt][nt][r] + bv;
                if (RELU) v = fmaxf(v, 0.f);
                C[(long long)row * 256 + col] = f2b(v);
            }
        }
    }
}

// ---------- final layer: 32 rows/block, out fp32 ----------
__global__ __launch_bounds__(256, 2) void fcf_kernel(
    const unsigned short* __restrict__ H,
    const float* __restrict__ W,
    const float* __restrict__ B,
    float* __restrict__ out, int row0)
{
    constexpr int LDW = 260;
    __shared__ float s_w[27 * LDW];
    __shared__ float s_bb[32];
    __shared__ unsigned short s_h[32 * 256];

    const int tid = threadIdx.x;
    for (int d = tid; d < 27 * 256; d += 256) {
        int o = d >> 8, k = d & 255;
        s_w[o * LDW + k] = W[d];
    }
    if (tid < 27) s_bb[tid] = B[tid];
    const int rl0 = blockIdx.x * 32;
    #pragma unroll
    for (int i = 0; i < 4; ++i) {
        int idx = tid + i * 256;             // 0..1023 uint4 chunks
        int row = idx >> 5, c8 = (idx & 31) * 8;
        *(uint4*)&s_h[row * 256 + c8] = *(const uint4*)&H[(long long)(rl0 + row) * 256 + c8];
    }
    __syncthreads();

    const int r8 = tid >> 5, o = tid & 31;
    if (o < 27) {
        #pragma unroll
        for (int rr = 0; rr < 4; ++rr) {
            const int rloc = rr * 8 + r8;
            const int grow = row0 + rl0 + rloc;
            if (grow < NPATCH) {
                float acc = s_bb[o];
                const unsigned short* hp = &s_h[rloc * 256];
                const float* wp = &s_w[o * LDW];
                #pragma unroll 4
                for (int k = 0; k < 256; k += 8) {
                    short8 hv = *(const short8*)&hp[k];
                    floatx4 w0 = *(const floatx4*)&wp[k];
                    floatx4 w1 = *(const floatx4*)&wp[k + 4];
                    acc = fmaf(b2f((unsigned short)hv[0]), w0[0], acc);
                    acc = fmaf(b2f((unsigned short)hv[1]), w0[1], acc);
                    acc = fmaf(b2f((unsigned short)hv[2]), w0[2], acc);
                    acc = fmaf(b2f((unsigned short)hv[3]), w0[3], acc);
                    acc = fmaf(b2f((unsigned short)hv[4]), w1[0], acc);
                    acc = fmaf(b2f((unsigned short)hv[5]), w1[1], acc);
                    acc = fmaf(b2f((unsigned short)hv[6]), w1[2], acc);
                    acc = fmaf(b2f((unsigned short)hv[7]), w1[3], acc);
                }
                out[(long long)grow * 27 + o] = acc;
            }
        }
    }
}

extern "C" void kernel_launch(void* const* d_in, const int* in_sizes, int n_in,
                              void* d_out, int out_size, void* d_ws, size_t ws_size,
                              hipStream_t stream) {
    const float* images = (const float*)d_in[0];
    const float* c1w = (const float*)d_in[1];
    const float* c1b = (const float*)d_in[2];
    const float* c2w = (const float*)d_in[3];
    const float* c2b = (const float*)d_in[4];
    const float* f1w = (const float*)d_in[5];
    const float* f1b = (const float*)d_in[6];
    const float* f2w = (const float*)d_in[7];
    const float* f2b_ = (const float*)d_in[8];
    const float* f3w = (const float*)d_in[9];
    const float* f3b = (const float*)d_in[10];
    const float* ffw = (const float*)d_in[11];
    const float* ffb = (const float*)d_in[12];

    const long long W1_E = 256LL * 1280, W2_E = 256LL * 256, W3_E = 256LL * 256;
    const long long W2T_E = 9LL * 32 * 32, W1T_E = 32LL * 32;
    const long long WB = (W1_E + W2_E + W3_E + W2T_E + W1T_E) * 2;
    char* ws = (char*)d_ws;
    unsigned short* W1  = (unsigned short*)ws;
    unsigned short* W2  = W1 + W1_E;
    unsigned short* W3  = W2 + W2_E;
    unsigned short* W2T = W3 + W3_E;
    unsigned short* W1T = W2T + W2T_E;

    // per 128-row block: X + H1 + H2 = 458752 B
    long long avail = (long long)ws_size - WB - 256;
    int nb_max = (int)(avail / 458752LL);
    if (nb_max < 1) nb_max = 1;
    if (nb_max > NBLK) nb_max = NBLK;
    // balance chunk sizes
    int nchunks = (NBLK + nb_max - 1) / nb_max;
    int nb_even = (NBLK + nchunks - 1) / nchunks;

    unsigned short* X  = (unsigned short*)(ws + WB);
    unsigned short* H1 = X  + (long long)nb_max * 128 * K1;
    unsigned short* H2 = H1 + (long long)nb_max * 128 * NH;

    to_bf16<<<(int)((W1_E + 255) / 256), 256, 0, stream>>>(f1w, W1, (int)W1_E);
    to_bf16<<<(int)((W2_E + 255) / 256), 256, 0, stream>>>(f2w, W2, (int)W2_E);
    to_bf16<<<(int)((W3_E + 255) / 256), 256, 0, stream>>>(f3w, W3, (int)W3_E);
    to_w1t<<<4, 256, 0, stream>>>(c1w, W1T);
    to_w2t<<<36, 256, 0, stream>>>(c2w, W2T);

    for (int b0 = 0; b0 < NBLK; b0 += nb_even) {
        int nb = NBLK - b0; if (nb > nb_even) nb = nb_even;
        int row0 = b0 * 128;
        int rows = nb * 128;

        conv_mfma<<<rows / 8, 256, 0, stream>>>(images, W1T, c1b, W2T, c2b, X, row0);

        gemm_full<1280, true><<<nb, 256, 0, stream>>>(X,  W1, f1b, H1);
        gemm_full<256,  true><<<nb, 256, 0, stream>>>(H1, W2, f2b_, H2);
        gemm_full<256,  true><<<nb, 256, 0, stream>>>(H2, W3, f3b, H1);

        fcf_kernel<<<rows / 32, 256, 0, stream>>>(H1, ffw, ffb, (float*)d_out, row0);
    }
}

// Round 7
// 407.369 us; speedup vs baseline: 1.9871x; 1.0982x over previous
//
#include <hip/hip_runtime.h>
#include <hip/hip_bf16.h>

// ---------- constants ----------
#define NPATCH 76832   // 32 * 49 * 49
#define NBLK   601     // ceil(NPATCH/128)
#define K1     1280    // 20*8*8
#define NH     256

typedef __attribute__((ext_vector_type(8))) short  short8;
typedef __attribute__((ext_vector_type(4))) float  floatx4;

__device__ __forceinline__ unsigned short f2b(float f) {
    unsigned int u = __builtin_bit_cast(unsigned int, f);
    u += 0x7FFFu + ((u >> 16) & 1u);   // RNE
    return (unsigned short)(u >> 16);
}
__device__ __forceinline__ float b2f(unsigned short h) {
    unsigned int u = ((unsigned int)h) << 16;
    return __builtin_bit_cast(float, u);
}
// HW packed f32x2 -> bf16x2 (v_cvt_pk_bf16_f32 on gfx950), a -> low
__device__ __forceinline__ unsigned int pk2(float a, float b) {
    __hip_bfloat162 h = __float22bfloat162_rn(make_float2(a, b));
    unsigned int u;
    __builtin_memcpy(&u, &h, 4);   // __hip_bfloat162 not trivially copyable -> no bit_cast
    return u;
}

// async global->LDS, 16B/lane; lds dest = wave-uniform base + lane*16
__device__ __forceinline__ void gload_lds16(const unsigned short* g, unsigned short* l) {
    __builtin_amdgcn_global_load_lds(
        (__attribute__((address_space(1))) void*)g,
        (__attribute__((address_space(3))) void*)l,
        16, 0, 0);
}

// swizzled chunk index within a 128B pixel-pair window
__device__ __host__ __forceinline__ int swz8(int row, int i) {
    return (((row & 1) * 4 + i) ^ ((row >> 1) & 7));
}

// ---------- weight fp32 -> bf16 ----------
__global__ void to_bf16(const float* __restrict__ src, unsigned short* __restrict__ dst, int n) {
    int i = blockIdx.x * 256 + threadIdx.x;
    if (i < n) dst[i] = f2b(src[i]);
}

// ---------- conv1 weights -> W1T[o:32][k:32] bf16, swizzled ----------
__global__ void to_w1t(const float* __restrict__ w1, unsigned short* __restrict__ dst) {
    int i = blockIdx.x * 256 + threadIdx.x;
    if (i >= 32 * 32) return;
    int o = i >> 5, k = i & 31;
    unsigned short v = 0;
    if (o < 20 && k < 18) v = f2b(w1[o * 18 + k]);   // k = c*9 + tap
    dst[(o >> 1) * 64 + swz8(o, k >> 3) * 8 + (k & 7)] = v;
}

// ---------- conv2 weights -> W2T[tap][o:32][c:32] bf16, swizzled ----------
__global__ void to_w2t(const float* __restrict__ w2, unsigned short* __restrict__ dst) {
    int i = blockIdx.x * 256 + threadIdx.x;
    if (i >= 9 * 32 * 32) return;
    int tap = i >> 10, rem = i & 1023, o = rem >> 5, c = rem & 31;
    unsigned short v = 0;
    if (o < 20 && c < 20) v = f2b(w2[o * 180 + c * 9 + tap]);
    dst[tap * 1024 + (o >> 1) * 64 + swz8(o, c >> 3) * 8 + (c & 7)] = v;
}

// ---------- fused tile + conv1(MFMA, A=W) + conv2(MFMA) ----------
// 256 threads = 8 patches/block; all per-patch work is wave-local -> ONE barrier.
__global__ __launch_bounds__(256, 3) void conv_mfma(
    const float* __restrict__ img,
    const unsigned short* __restrict__ W1T, const float* __restrict__ b1,
    const unsigned short* __restrict__ W2T, const float* __restrict__ b2,
    unsigned short* __restrict__ X, int row0)
{
    __shared__ alignas(16) unsigned short s_buf[8 * 2048 + 64];
    __shared__ alignas(16) unsigned short s_w1t[1024];
    __shared__ alignas(16) unsigned short s_w2t[9216];
    __shared__ float s_b1[32], s_b2[32];
    constexpr int ZOFF = 8 * 2048;

    const int tid = threadIdx.x;
    for (int d = tid; d < 512; d += 256)  ((unsigned int*)s_w1t)[d] = ((const unsigned int*)W1T)[d];
    for (int d = tid; d < 4608; d += 256) ((unsigned int*)s_w2t)[d] = ((const unsigned int*)W2T)[d];
    if (tid < 32) {
        ((unsigned int*)&s_buf[ZOFF])[tid] = 0u;
        s_b1[tid] = (tid < 20) ? b1[tid] : 0.f;
        s_b2[tid] = (tid < 20) ? b2[tid] : 0.f;
    }

    // ---- gather: A1[pix][k] bf16 (per-patch zero-pad), swizzled; wave-local patches ----
    const int q = tid >> 5, t = tid & 31;
    const int Pl = blockIdx.x * 8 + q;
    const int Pi = row0 + Pl;
    const bool valid = Pi < NPATCH;
    int b = 0, hi = 0, wi = 0;
    if (valid) { b = Pi / 2401; int rem = Pi - b * 2401; hi = rem / 49; wi = rem - hi * 49; }
    const int py = t >> 2, px0 = (t & 3) * 2;
    const float* ib = img + (long long)b * 21632 + (hi * 2) * 104 + (wi * 2);

    float win[2][3][4];
    #pragma unroll
    for (int c = 0; c < 2; ++c)
        #pragma unroll
        for (int dy = 0; dy < 3; ++dy) {
            int ny = py + dy - 1;
            int nyc = ny < 0 ? 0 : (ny > 7 ? 7 : ny);
            #pragma unroll
            for (int dxw = 0; dxw < 4; ++dxw) {
                int nx = px0 + dxw - 1;
                int nxc = nx < 0 ? 0 : (nx > 7 ? 7 : nx);
                win[c][dy][dxw] = ib[c * 10816 + nyc * 104 + nxc];
            }
        }

    #pragma unroll
    for (int j = 0; j < 2; ++j) {
        const int px = px0 + j, pl = py * 8 + px;
        float val[18];
        #pragma unroll
        for (int c = 0; c < 2; ++c)
            #pragma unroll
            for (int dy = 0; dy < 3; ++dy) {
                int ny = py + dy - 1;
                bool rok = valid && ((unsigned)ny < 8u);
                #pragma unroll
                for (int dx = 0; dx < 3; ++dx) {
                    int nx = px + dx - 1;
                    bool ok = rok && ((unsigned)nx < 8u);
                    val[c * 9 + dy * 3 + dx] = ok ? win[c][dy][dx + j] : 0.f;
                }
            }
        alignas(16) unsigned int au[16];
        #pragma unroll
        for (int i = 0; i < 9; ++i) au[i] = pk2(val[2 * i], val[2 * i + 1]);
        #pragma unroll
        for (int i = 9; i < 16; ++i) au[i] = 0u;
        unsigned short* base = &s_buf[q * 2048 + (pl >> 1) * 64];
        #pragma unroll
        for (int i = 0; i < 4; ++i)
            *(uint4*)&base[swz8(pl, i) * 8] = ((const uint4*)au)[i];
    }
    __syncthreads();   // the only barrier: weights/biases/zero-row + A1 visible

    const int wave = tid >> 6, lane = tid & 63;
    const int l15 = lane & 15, quad = lane >> 4;
    const int p0 = wave * 2;

    int boffB[2];      // o-row fragment offsets (shared by w1t A-frags and w2t B-frags)
    #pragma unroll
    for (int i = 0; i < 2; ++i) {
        int oo = i * 16 + l15;
        boffB[i] = (oo >> 1) * 64 + swz8(oo, quad) * 8;
    }

    // ---- conv1 MFMA: A = W1T (rows=o), B = pixels -> C[o][pix] ----
    short8 a1f[2];
    #pragma unroll
    for (int mt = 0; mt < 2; ++mt) a1f[mt] = *(const short8*)&s_w1t[boffB[mt]];

    floatx4 acc1[2][2][4] = {};   // [pp][o-tile][pix-tile]
    #pragma unroll
    for (int pp = 0; pp < 2; ++pp)
        #pragma unroll
        for (int nt = 0; nt < 4; ++nt) {
            int pix = nt * 16 + l15;
            short8 pf = *(const short8*)&s_buf[(p0 + pp) * 2048 + (pix >> 1) * 64 + swz8(pix, quad) * 8];
            #pragma unroll
            for (int mt = 0; mt < 2; ++mt)
                acc1[pp][mt][nt] = __builtin_amdgcn_mfma_f32_16x16x32_bf16(a1f[mt], pf, acc1[pp][mt][nt], 0, 0, 0);
        }

    // ---- h1 = relu(conv1+b1) -> same wave-local region, [pix][32ch] swizzled, b64 writes ----
    float bv1[2][4];
    #pragma unroll
    for (int mt = 0; mt < 2; ++mt)
        #pragma unroll
        for (int r = 0; r < 4; ++r) bv1[mt][r] = s_b1[mt * 16 + quad * 4 + r];

    #pragma unroll
    for (int pp = 0; pp < 2; ++pp)
        #pragma unroll
        for (int mt = 0; mt < 2; ++mt)
            #pragma unroll
            for (int nt = 0; nt < 4; ++nt) {
                floatx4 v = acc1[pp][mt][nt];
                uint2 w;
                w.x = pk2(fmaxf(v[0] + bv1[mt][0], 0.f), fmaxf(v[1] + bv1[mt][1], 0.f));
                w.y = pk2(fmaxf(v[2] + bv1[mt][2], 0.f), fmaxf(v[3] + bv1[mt][3], 0.f));
                int pix = nt * 16 + l15;
                int off = (p0 + pp) * 2048 + (pix >> 1) * 64
                        + swz8(pix, mt * 2 + (quad >> 1)) * 8 + (quad & 1) * 4;
                *(uint2*)&s_buf[off] = w;
            }
    // no barrier: conv2 reads only this wave's patches (per-patch padding)

    // ---- conv2 MFMA (tap loop): A = h1 pixels, B = W2T -> C[pix][o] ----
    int syv[4], pxv[4];
    #pragma unroll
    for (int mt = 0; mt < 4; ++mt) { int p = mt * 16 + l15; syv[mt] = p >> 3; pxv[mt] = p & 7; }

    floatx4 acc2[2][4][2] = {};
    #pragma unroll 1
    for (int dy = 0; dy < 3; ++dy) {
        int sy[4]; bool okY[4];
        #pragma unroll
        for (int mt = 0; mt < 4; ++mt) {
            sy[mt] = syv[mt] + dy - 1;
            okY[mt] = (unsigned)sy[mt] < 8u;
        }
        #pragma unroll
        for (int dx = 0; dx < 3; ++dx) {
            const int tap = dy * 3 + dx;
            short8 bf0 = *(const short8*)&s_w2t[tap * 1024 + boffB[0]];
            short8 bf1 = *(const short8*)&s_w2t[tap * 1024 + boffB[1]];
            #pragma unroll
            for (int mt = 0; mt < 4; ++mt) {
                int sx = pxv[mt] + dx - 1;
                bool ok = okY[mt] & ((unsigned)sx < 8u);
                int ps = sy[mt] * 8 + sx;
                int offl = (ps >> 1) * 64 + swz8(ps, quad) * 8;
                #pragma unroll
                for (int pp = 0; pp < 2; ++pp) {
                    int off = ok ? ((p0 + pp) * 2048 + offl) : (ZOFF + quad * 8);
                    short8 af = *(const short8*)&s_buf[off];
                    acc2[pp][mt][0] = __builtin_amdgcn_mfma_f32_16x16x32_bf16(af, bf0, acc2[pp][mt][0], 0, 0, 0);
                    acc2[pp][mt][1] = __builtin_amdgcn_mfma_f32_16x16x32_bf16(af, bf1, acc2[pp][mt][1], 0, 0, 0);
                }
            }
        }
    }

    // ---- epilogue: bias+relu+bf16 pack, X[Pl][o*64+pix], 8B stores ----
    #pragma unroll
    for (int pp = 0; pp < 2; ++pp) {
        unsigned short* xrow = X + (long long)(blockIdx.x * 8 + p0 + pp) * K1;
        #pragma unroll
        for (int nt = 0; nt < 2; ++nt) {
            const int col = nt * 16 + l15;
            if (col < 20) {
                const float bv = s_b2[col];
                #pragma unroll
                for (int mt = 0; mt < 4; ++mt) {
                    floatx4 v = acc2[pp][mt][nt];
                    uint2 w;
                    w.x = pk2(fmaxf(v[0] + bv, 0.f), fmaxf(v[1] + bv, 0.f));
                    w.y = pk2(fmaxf(v[2] + bv, 0.f), fmaxf(v[3] + bv, 0.f));
                    *(uint2*)&xrow[col * 64 + mt * 16 + quad * 4] = w;
                }
            }
        }
    }
}

// ---------- M=64 x N=256 bf16 MFMA GEMM, XOR-swizzled async staging ----------
// C[rows][256] = relu(A[rows][K] @ W[256][K]^T + bias); grid = rows/64
template<int K, bool RELU>
__global__ __launch_bounds__(256, 3) void gemm64(
    const unsigned short* __restrict__ A,
    const unsigned short* __restrict__ W,
    const float* __restrict__ bias,
    unsigned short* __restrict__ C)
{
    __shared__ alignas(16) unsigned short s_a[64 * 64];    // 8 KB
    __shared__ alignas(16) unsigned short s_b[256 * 64];   // 32 KB

    const int tid = threadIdx.x;
    const int m0 = blockIdx.x * 64;
    const int wave = tid >> 6, lane = tid & 63;
    const int l15 = lane & 15, quad = lane >> 4;
    const int lrow = lane >> 3, lchunk = lane & 7;

    floatx4 acc[4][4] = {};

    #pragma unroll 1
    for (int kt = 0; kt < K; kt += 64) {
        // staging: LDS [row][chunk-pos], source chunk = pos ^ (row&7)  (same 128B line)
        #pragma unroll
        for (int i = 0; i < 2; ++i) {
            int br = wave * 16 + i * 8;
            int r = br + lrow;
            gload_lds16(A + (long long)(m0 + r) * K + kt + (lchunk ^ (r & 7)) * 8, &s_a[br * 64]);
        }
        #pragma unroll
        for (int i = 0; i < 8; ++i) {
            int br = wave * 64 + i * 8;
            int r = br + lrow;
            gload_lds16(W + (long long)r * K + kt + (lchunk ^ (r & 7)) * 8, &s_b[br * 64]);
        }
        __syncthreads();
        #pragma unroll
        for (int kh = 0; kh < 2; ++kh) {
            short8 af[4], bf[4];
            #pragma unroll
            for (int mt = 0; mt < 4; ++mt) {
                int r = mt * 16 + l15;
                af[mt] = *(const short8*)&s_a[r * 64 + (((kh * 4 + quad) ^ (r & 7)) * 8)];
            }
            #pragma unroll
            for (int nt = 0; nt < 4; ++nt) {
                int r = wave * 64 + nt * 16 + l15;
                bf[nt] = *(const short8*)&s_b[r * 64 + (((kh * 4 + quad) ^ (r & 7)) * 8)];
            }
            #pragma unroll
            for (int mt = 0; mt < 4; ++mt)
                #pragma unroll
                for (int nt = 0; nt < 4; ++nt)
                    acc[mt][nt] = __builtin_amdgcn_mfma_f32_16x16x32_bf16(af[mt], bf[nt], acc[mt][nt], 0, 0, 0);
        }
        __syncthreads();
    }

    #pragma unroll
    for (int nt = 0; nt < 4; ++nt) {
        const int col = wave * 64 + nt * 16 + l15;
        const float bv = bias[col];
        #pragma unroll
        for (int mt = 0; mt < 4; ++mt) {
            #pragma unroll
            for (int r = 0; r < 4; ++r) {
                int row = m0 + mt * 16 + quad * 4 + r;
                float v = acc[mt][nt][r] + bv;
                if (RELU) v = fmaxf(v, 0.f);
                C[(long long)row * 256 + col] = f2b(v);
            }
        }
    }
}

// ---------- final layer: 32 rows/block, out fp32 ----------
__global__ __launch_bounds__(256, 2) void fcf_kernel(
    const unsigned short* __restrict__ H,
    const float* __restrict__ W,
    const float* __restrict__ B,
    float* __restrict__ out, int row0)
{
    constexpr int LDW = 260;
    __shared__ float s_w[27 * LDW];
    __shared__ float s_bb[32];
    __shared__ unsigned short s_h[32 * 256];

    const int tid = threadIdx.x;
    for (int d = tid; d < 27 * 256; d += 256) {
        int o = d >> 8, k = d & 255;
        s_w[o * LDW + k] = W[d];
    }
    if (tid < 27) s_bb[tid] = B[tid];
    const int rl0 = blockIdx.x * 32;
    #pragma unroll
    for (int i = 0; i < 4; ++i) {
        int idx = tid + i * 256;
        int row = idx >> 5, c8 = (idx & 31) * 8;
        *(uint4*)&s_h[row * 256 + c8] = *(const uint4*)&H[(long long)(rl0 + row) * 256 + c8];
    }
    __syncthreads();

    const int r8 = tid >> 5, o = tid & 31;
    if (o < 27) {
        #pragma unroll
        for (int rr = 0; rr < 4; ++rr) {
            const int rloc = rr * 8 + r8;
            const int grow = row0 + rl0 + rloc;
            if (grow < NPATCH) {
                float acc = s_bb[o];
                const unsigned short* hp = &s_h[rloc * 256];
                const float* wp = &s_w[o * LDW];
                #pragma unroll 4
                for (int k = 0; k < 256; k += 8) {
                    short8 hv = *(const short8*)&hp[k];
                    floatx4 w0 = *(const floatx4*)&wp[k];
                    floatx4 w1 = *(const floatx4*)&wp[k + 4];
                    acc = fmaf(b2f((unsigned short)hv[0]), w0[0], acc);
                    acc = fmaf(b2f((unsigned short)hv[1]), w0[1], acc);
                    acc = fmaf(b2f((unsigned short)hv[2]), w0[2], acc);
                    acc = fmaf(b2f((unsigned short)hv[3]), w0[3], acc);
                    acc = fmaf(b2f((unsigned short)hv[4]), w1[0], acc);
                    acc = fmaf(b2f((unsigned short)hv[5]), w1[1], acc);
                    acc = fmaf(b2f((unsigned short)hv[6]), w1[2], acc);
                    acc = fmaf(b2f((unsigned short)hv[7]), w1[3], acc);
                }
                out[(long long)grow * 27 + o] = acc;
            }
        }
    }
}

extern "C" void kernel_launch(void* const* d_in, const int* in_sizes, int n_in,
                              void* d_out, int out_size, void* d_ws, size_t ws_size,
                              hipStream_t stream) {
    const float* images = (const float*)d_in[0];
    const float* c1w = (const float*)d_in[1];
    const float* c1b = (const float*)d_in[2];
    const float* c2w = (const float*)d_in[3];
    const float* c2b = (const float*)d_in[4];
    const float* f1w = (const float*)d_in[5];
    const float* f1b = (const float*)d_in[6];
    const float* f2w = (const float*)d_in[7];
    const float* f2b_ = (const float*)d_in[8];
    const float* f3w = (const float*)d_in[9];
    const float* f3b = (const float*)d_in[10];
    const float* ffw = (const float*)d_in[11];
    const float* ffb = (const float*)d_in[12];

    const long long W1_E = 256LL * 1280, W2_E = 256LL * 256, W3_E = 256LL * 256;
    const long long W2T_E = 9LL * 32 * 32, W1T_E = 32LL * 32;
    const long long WB = (W1_E + W2_E + W3_E + W2T_E + W1T_E) * 2;
    char* ws = (char*)d_ws;
    unsigned short* W1  = (unsigned short*)ws;
    unsigned short* W2  = W1 + W1_E;
    unsigned short* W3  = W2 + W2_E;
    unsigned short* W2T = W3 + W3_E;
    unsigned short* W1T = W2T + W2T_E;

    // per 128-row block: X + H1 + H2 = 458752 B
    long long avail = (long long)ws_size - WB - 256;
    int nb_max = (int)(avail / 458752LL);
    if (nb_max < 1) nb_max = 1;
    if (nb_max > NBLK) nb_max = NBLK;
    int nchunks = (NBLK + nb_max - 1) / nb_max;
    int nb_even = (NBLK + nchunks - 1) / nchunks;

    unsigned short* X  = (unsigned short*)(ws + WB);
    unsigned short* H1 = X  + (long long)nb_max * 128 * K1;
    unsigned short* H2 = H1 + (long long)nb_max * 128 * NH;

    to_bf16<<<(int)((W1_E + 255) / 256), 256, 0, stream>>>(f1w, W1, (int)W1_E);
    to_bf16<<<(int)((W2_E + 255) / 256), 256, 0, stream>>>(f2w, W2, (int)W2_E);
    to_bf16<<<(int)((W3_E + 255) / 256), 256, 0, stream>>>(f3w, W3, (int)W3_E);
    to_w1t<<<4, 256, 0, stream>>>(c1w, W1T);
    to_w2t<<<36, 256, 0, stream>>>(c2w, W2T);

    for (int b0 = 0; b0 < NBLK; b0 += nb_even) {
        int nb = NBLK - b0; if (nb > nb_even) nb = nb_even;
        int row0 = b0 * 128;
        int rows = nb * 128;

        conv_mfma<<<rows / 8, 256, 0, stream>>>(images, W1T, c1b, W2T, c2b, X, row0);

        gemm64<1280, true><<<nb * 2, 256, 0, stream>>>(X,  W1, f1b, H1);
        gemm64<256,  true><<<nb * 2, 256, 0, stream>>>(H1, W2, f2b_, H2);
        gemm64<256,  true><<<nb * 2, 256, 0, stream>>>(H2, W3, f3b, H1);

        fcf_kernel<<<rows / 32, 256, 0, stream>>>(H1, ffw, ffb, (float*)d_out, row0);
    }
}

// Round 9
// 332.828 us; speedup vs baseline: 2.4321x; 1.2240x over previous
//
#include <hip/hip_runtime.h>
#include <hip/hip_bf16.h>

// ---------- constants ----------
#define NPATCH 76832   // 32 * 49 * 49
#define NBLK   601     // ceil(NPATCH/128)
#define K1     1280    // 20*8*8

typedef __attribute__((ext_vector_type(8))) short  short8;
typedef __attribute__((ext_vector_type(4))) float  floatx4;

__device__ __forceinline__ unsigned short f2b(float f) {
    unsigned int u = __builtin_bit_cast(unsigned int, f);
    u += 0x7FFFu + ((u >> 16) & 1u);   // RNE
    return (unsigned short)(u >> 16);
}
__device__ __forceinline__ float b2f(unsigned short h) {
    unsigned int u = ((unsigned int)h) << 16;
    return __builtin_bit_cast(float, u);
}
// HW packed f32x2 -> bf16x2 (v_cvt_pk_bf16_f32), a -> low
__device__ __forceinline__ unsigned int pk2(float a, float b) {
    __hip_bfloat162 h = __float22bfloat162_rn(make_float2(a, b));
    unsigned int u;
    __builtin_memcpy(&u, &h, 4);
    return u;
}

// async global->LDS, 16B/lane; global addr is PER-LANE, lds dest = wave-uniform base + lane*16
__device__ __forceinline__ void gload_lds16(const unsigned short* g, unsigned short* l) {
    __builtin_amdgcn_global_load_lds(
        (__attribute__((address_space(1))) void*)g,
        (__attribute__((address_space(3))) void*)l,
        16, 0, 0);
}

// swizzled chunk index within a 128B pixel-pair window (conv layout)
__device__ __host__ __forceinline__ int swz8(int row, int i) {
    return (((row & 1) * 4 + i) ^ ((row >> 1) & 7));
}

// ---------- single prep kernel: all weight conversions ----------
// sections: W1(327680) W2(65536) W3(65536) W1T(1024) W2T(9216) WfB(8192)
__global__ void prep(const float* __restrict__ f1w, const float* __restrict__ f2w,
                     const float* __restrict__ f3w, const float* __restrict__ c1w,
                     const float* __restrict__ c2w, const float* __restrict__ ffw,
                     unsigned short* __restrict__ W1, unsigned short* __restrict__ W2,
                     unsigned short* __restrict__ W3, unsigned short* __restrict__ W1T,
                     unsigned short* __restrict__ W2T, unsigned short* __restrict__ WfB) {
    int i = blockIdx.x * 256 + threadIdx.x;
    if (i < 327680) { W1[i] = f2b(f1w[i]); return; }
    i -= 327680;
    if (i < 65536) { W2[i] = f2b(f2w[i]); return; }
    i -= 65536;
    if (i < 65536) { W3[i] = f2b(f3w[i]); return; }
    i -= 65536;
    if (i < 1024) {            // W1T[o:32][k:32], conv swizzle
        int o = i >> 5, k = i & 31;
        unsigned short v = 0;
        if (o < 20 && k < 18) v = f2b(c1w[o * 18 + k]);
        W1T[(o >> 1) * 64 + swz8(o, k >> 3) * 8 + (k & 7)] = v;
        return;
    }
    i -= 1024;
    if (i < 9216) {            // W2T[tap][o:32][c:32], conv swizzle
        int tap = i >> 10, rem = i & 1023, o = rem >> 5, c = rem & 31;
        unsigned short v = 0;
        if (o < 20 && c < 20) v = f2b(c2w[o * 180 + c * 9 + tap]);
        W2T[tap * 1024 + (o >> 1) * 64 + swz8(o, c >> 3) * 8 + (c & 7)] = v;
        return;
    }
    i -= 9216;
    if (i < 8192) {            // WfB[o:32][k:256] bf16, chunk-XOR swizzled by o
        int o = i >> 8, k = i & 255;
        unsigned short v = (o < 27) ? f2b(ffw[o * 256 + k]) : (unsigned short)0;
        int c = k >> 3, pos = (c & ~7) | ((c & 7) ^ (o & 7));
        WfB[o * 256 + pos * 8 + (k & 7)] = v;
    }
}

// ---------- fused tile + conv1(MFMA) + conv2(MFMA) (unchanged from R7) ----------
__global__ __launch_bounds__(256, 3) void conv_mfma(
    const float* __restrict__ img,
    const unsigned short* __restrict__ W1T, const float* __restrict__ b1,
    const unsigned short* __restrict__ W2T, const float* __restrict__ b2,
    unsigned short* __restrict__ X, int row0)
{
    __shared__ alignas(16) unsigned short s_buf[8 * 2048 + 64];
    __shared__ alignas(16) unsigned short s_w1t[1024];
    __shared__ alignas(16) unsigned short s_w2t[9216];
    __shared__ float s_b1[32], s_b2[32];
    constexpr int ZOFF = 8 * 2048;

    const int tid = threadIdx.x;
    for (int d = tid; d < 512; d += 256)  ((unsigned int*)s_w1t)[d] = ((const unsigned int*)W1T)[d];
    for (int d = tid; d < 4608; d += 256) ((unsigned int*)s_w2t)[d] = ((const unsigned int*)W2T)[d];
    if (tid < 32) {
        ((unsigned int*)&s_buf[ZOFF])[tid] = 0u;
        s_b1[tid] = (tid < 20) ? b1[tid] : 0.f;
        s_b2[tid] = (tid < 20) ? b2[tid] : 0.f;
    }

    const int q = tid >> 5, t = tid & 31;
    const int Pl = blockIdx.x * 8 + q;
    const int Pi = row0 + Pl;
    const bool valid = Pi < NPATCH;
    int b = 0, hi = 0, wi = 0;
    if (valid) { b = Pi / 2401; int rem = Pi - b * 2401; hi = rem / 49; wi = rem - hi * 49; }
    const int py = t >> 2, px0 = (t & 3) * 2;
    const float* ib = img + (long long)b * 21632 + (hi * 2) * 104 + (wi * 2);

    float win[2][3][4];
    #pragma unroll
    for (int c = 0; c < 2; ++c)
        #pragma unroll
        for (int dy = 0; dy < 3; ++dy) {
            int ny = py + dy - 1;
            int nyc = ny < 0 ? 0 : (ny > 7 ? 7 : ny);
            #pragma unroll
            for (int dxw = 0; dxw < 4; ++dxw) {
                int nx = px0 + dxw - 1;
                int nxc = nx < 0 ? 0 : (nx > 7 ? 7 : nx);
                win[c][dy][dxw] = ib[c * 10816 + nyc * 104 + nxc];
            }
        }

    #pragma unroll
    for (int j = 0; j < 2; ++j) {
        const int px = px0 + j, pl = py * 8 + px;
        float val[18];
        #pragma unroll
        for (int c = 0; c < 2; ++c)
            #pragma unroll
            for (int dy = 0; dy < 3; ++dy) {
                int ny = py + dy - 1;
                bool rok = valid && ((unsigned)ny < 8u);
                #pragma unroll
                for (int dx = 0; dx < 3; ++dx) {
                    int nx = px + dx - 1;
                    bool ok = rok && ((unsigned)nx < 8u);
                    val[c * 9 + dy * 3 + dx] = ok ? win[c][dy][dx + j] : 0.f;
                }
            }
        alignas(16) unsigned int au[16];
        #pragma unroll
        for (int i = 0; i < 9; ++i) au[i] = pk2(val[2 * i], val[2 * i + 1]);
        #pragma unroll
        for (int i = 9; i < 16; ++i) au[i] = 0u;
        unsigned short* base = &s_buf[q * 2048 + (pl >> 1) * 64];
        #pragma unroll
        for (int i = 0; i < 4; ++i)
            *(uint4*)&base[swz8(pl, i) * 8] = ((const uint4*)au)[i];
    }
    __syncthreads();

    const int wave = tid >> 6, lane = tid & 63;
    const int l15 = lane & 15, quad = lane >> 4;
    const int p0 = wave * 2;

    int boffB[2];
    #pragma unroll
    for (int i = 0; i < 2; ++i) {
        int oo = i * 16 + l15;
        boffB[i] = (oo >> 1) * 64 + swz8(oo, quad) * 8;
    }

    short8 a1f[2];
    #pragma unroll
    for (int mt = 0; mt < 2; ++mt) a1f[mt] = *(const short8*)&s_w1t[boffB[mt]];

    floatx4 acc1[2][2][4] = {};
    #pragma unroll
    for (int pp = 0; pp < 2; ++pp)
        #pragma unroll
        for (int nt = 0; nt < 4; ++nt) {
            int pix = nt * 16 + l15;
            short8 pf = *(const short8*)&s_buf[(p0 + pp) * 2048 + (pix >> 1) * 64 + swz8(pix, quad) * 8];
            #pragma unroll
            for (int mt = 0; mt < 2; ++mt)
                acc1[pp][mt][nt] = __builtin_amdgcn_mfma_f32_16x16x32_bf16(a1f[mt], pf, acc1[pp][mt][nt], 0, 0, 0);
        }

    float bv1[2][4];
    #pragma unroll
    for (int mt = 0; mt < 2; ++mt)
        #pragma unroll
        for (int r = 0; r < 4; ++r) bv1[mt][r] = s_b1[mt * 16 + quad * 4 + r];

    #pragma unroll
    for (int pp = 0; pp < 2; ++pp)
        #pragma unroll
        for (int mt = 0; mt < 2; ++mt)
            #pragma unroll
            for (int nt = 0; nt < 4; ++nt) {
                floatx4 v = acc1[pp][mt][nt];
                uint2 w;
                w.x = pk2(fmaxf(v[0] + bv1[mt][0], 0.f), fmaxf(v[1] + bv1[mt][1], 0.f));
                w.y = pk2(fmaxf(v[2] + bv1[mt][2], 0.f), fmaxf(v[3] + bv1[mt][3], 0.f));
                int pix = nt * 16 + l15;
                int off = (p0 + pp) * 2048 + (pix >> 1) * 64
                        + swz8(pix, mt * 2 + (quad >> 1)) * 8 + (quad & 1) * 4;
                *(uint2*)&s_buf[off] = w;
            }

    int syv[4], pxv[4];
    #pragma unroll
    for (int mt = 0; mt < 4; ++mt) { int p = mt * 16 + l15; syv[mt] = p >> 3; pxv[mt] = p & 7; }

    floatx4 acc2[2][4][2] = {};
    #pragma unroll 1
    for (int dy = 0; dy < 3; ++dy) {
        int sy[4]; bool okY[4];
        #pragma unroll
        for (int mt = 0; mt < 4; ++mt) {
            sy[mt] = syv[mt] + dy - 1;
            okY[mt] = (unsigned)sy[mt] < 8u;
        }
        #pragma unroll
        for (int dx = 0; dx < 3; ++dx) {
            const int tap = dy * 3 + dx;
            short8 bf0 = *(const short8*)&s_w2t[tap * 1024 + boffB[0]];
            short8 bf1 = *(const short8*)&s_w2t[tap * 1024 + boffB[1]];
            #pragma unroll
            for (int mt = 0; mt < 4; ++mt) {
                int sx = pxv[mt] + dx - 1;
                bool ok = okY[mt] & ((unsigned)sx < 8u);
                int ps = sy[mt] * 8 + sx;
                int offl = (ps >> 1) * 64 + swz8(ps, quad) * 8;
                #pragma unroll
                for (int pp = 0; pp < 2; ++pp) {
                    int off = ok ? ((p0 + pp) * 2048 + offl) : (ZOFF + quad * 8);
                    short8 af = *(const short8*)&s_buf[off];
                    acc2[pp][mt][0] = __builtin_amdgcn_mfma_f32_16x16x32_bf16(af, bf0, acc2[pp][mt][0], 0, 0, 0);
                    acc2[pp][mt][1] = __builtin_amdgcn_mfma_f32_16x16x32_bf16(af, bf1, acc2[pp][mt][1], 0, 0, 0);
                }
            }
        }
    }

    #pragma unroll
    for (int pp = 0; pp < 2; ++pp) {
        unsigned short* xrow = X + (long long)(blockIdx.x * 8 + p0 + pp) * K1;
        #pragma unroll
        for (int nt = 0; nt < 2; ++nt) {
            const int col = nt * 16 + l15;
            if (col < 20) {
                const float bv = s_b2[col];
                #pragma unroll
                for (int mt = 0; mt < 4; ++mt) {
                    floatx4 v = acc2[pp][mt][nt];
                    uint2 w;
                    w.x = pk2(fmaxf(v[0] + bv, 0.f), fmaxf(v[1] + bv, 0.f));
                    w.y = pk2(fmaxf(v[2] + bv, 0.f), fmaxf(v[3] + bv, 0.f));
                    *(uint2*)&xrow[col * 64 + mt * 16 + quad * 4] = w;
                }
            }
        }
    }
}

// ---------- fc_all: fc1 -> fc2 -> fc3 -> fcf for 64 rows/block ----------
// MFMA operands swapped (A = weights, B = data-rows) so C = [col][row];
// h kept in one 32KB LDS buffer, chunk-XOR swizzled: pos = (c&~7)|((c&7)^(row&7)).
__global__ __launch_bounds__(256, 2) void fc_all(
    const unsigned short* __restrict__ X,
    const unsigned short* __restrict__ W1, const unsigned short* __restrict__ W2,
    const unsigned short* __restrict__ W3, const unsigned short* __restrict__ WfB,
    const float* __restrict__ b1, const float* __restrict__ b2,
    const float* __restrict__ b3, const float* __restrict__ bf_,
    float* __restrict__ out, int row0)
{
    __shared__ alignas(16) unsigned short s_a[64 * 64];     // 8 KB  (X staging)
    __shared__ alignas(16) unsigned short s_b[256 * 64];    // 32 KB (W staging / WfB)
    __shared__ alignas(16) unsigned short s_h[64 * 256];    // 32 KB (h1/h2/h3)

    const int tid = threadIdx.x;
    const int m0 = blockIdx.x * 64;
    const int wave = tid >> 6, lane = tid & 63;
    const int l15 = lane & 15, quad = lane >> 4;
    const int lrow = lane >> 3, lchunk = lane & 7;

    floatx4 acc[4][4];

    // ================= fc1: A=W1[256][1280], B=X rows =================
    #pragma unroll
    for (int mt = 0; mt < 4; ++mt)
        #pragma unroll
        for (int nt = 0; nt < 4; ++nt) acc[mt][nt] = floatx4{0.f, 0.f, 0.f, 0.f};

    #pragma unroll 1
    for (int kt = 0; kt < 1280; kt += 64) {
        #pragma unroll
        for (int i = 0; i < 2; ++i) {
            int br = wave * 16 + i * 8, r = br + lrow;
            gload_lds16(X + (long long)(m0 + r) * 1280 + kt + (lchunk ^ (r & 7)) * 8, &s_a[br * 64]);
        }
        #pragma unroll
        for (int i = 0; i < 8; ++i) {
            int br = wave * 64 + i * 8, r = br + lrow;
            gload_lds16(W1 + (long long)r * 1280 + kt + (lchunk ^ (r & 7)) * 8, &s_b[br * 64]);
        }
        __syncthreads();
        #pragma unroll
        for (int kh = 0; kh < 2; ++kh) {
            short8 af[4], bf[4];
            #pragma unroll
            for (int mt = 0; mt < 4; ++mt) {
                int r = wave * 64 + mt * 16 + l15;   // W1 row = output col
                af[mt] = *(const short8*)&s_b[r * 64 + (((kh * 4 + quad) ^ (r & 7)) * 8)];
            }
            #pragma unroll
            for (int nt = 0; nt < 4; ++nt) {
                int r = nt * 16 + l15;               // X row
                bf[nt] = *(const short8*)&s_a[r * 64 + (((kh * 4 + quad) ^ (r & 7)) * 8)];
            }
            #pragma unroll
            for (int mt = 0; mt < 4; ++mt)
                #pragma unroll
                for (int nt = 0; nt < 4; ++nt)
                    acc[mt][nt] = __builtin_amdgcn_mfma_f32_16x16x32_bf16(af[mt], bf[nt], acc[mt][nt], 0, 0, 0);
        }
        __syncthreads();
    }
    // write h1 = relu(acc + b1) into s_h  (C[o][row]: reg r -> o, l15 -> row)
    {
        #pragma unroll
        for (int mt = 0; mt < 4; ++mt) {
            int obase = wave * 64 + mt * 16 + quad * 4;
            float v0 = b1[obase], v1 = b1[obase + 1], v2 = b1[obase + 2], v3 = b1[obase + 3];
            int clow = mt * 2 + (quad >> 1), sub = (quad & 1) * 4;
            #pragma unroll
            for (int nt = 0; nt < 4; ++nt) {
                int row = nt * 16 + l15;
                int pos = wave * 8 + (clow ^ (row & 7));
                floatx4 v = acc[mt][nt];
                uint2 w;
                w.x = pk2(fmaxf(v[0] + v0, 0.f), fmaxf(v[1] + v1, 0.f));
                w.y = pk2(fmaxf(v[2] + v2, 0.f), fmaxf(v[3] + v3, 0.f));
                *(uint2*)&s_h[row * 256 + pos * 8 + sub] = w;
            }
        }
    }
    __syncthreads();

    // ================= fc2 / fc3: A=W[256][256], B=h rows (LDS) =================
    #pragma unroll 1
    for (int layer = 0; layer < 2; ++layer) {
        const unsigned short* Wp = (layer == 0) ? W2 : W3;
        const float* bp = (layer == 0) ? b2 : b3;

        #pragma unroll
        for (int mt = 0; mt < 4; ++mt)
            #pragma unroll
            for (int nt = 0; nt < 4; ++nt) acc[mt][nt] = floatx4{0.f, 0.f, 0.f, 0.f};

        #pragma unroll 1
        for (int kt2 = 0; kt2 < 4; ++kt2) {
            #pragma unroll
            for (int i = 0; i < 8; ++i) {
                int br = wave * 64 + i * 8, r = br + lrow;
                gload_lds16(Wp + (long long)r * 256 + kt2 * 64 + (lchunk ^ (r & 7)) * 8, &s_b[br * 64]);
            }
            __syncthreads();
            #pragma unroll
            for (int kh = 0; kh < 2; ++kh) {
                short8 af[4], bf[4];
                #pragma unroll
                for (int mt = 0; mt < 4; ++mt) {
                    int r = wave * 64 + mt * 16 + l15;
                    af[mt] = *(const short8*)&s_b[r * 64 + (((kh * 4 + quad) ^ (r & 7)) * 8)];
                }
                #pragma unroll
                for (int nt = 0; nt < 4; ++nt) {
                    int row = nt * 16 + l15;
                    int pos = kt2 * 8 + ((kh * 4 + quad) ^ (row & 7));
                    bf[nt] = *(const short8*)&s_h[row * 256 + pos * 8];
                }
                #pragma unroll
                for (int mt = 0; mt < 4; ++mt)
                    #pragma unroll
                    for (int nt = 0; nt < 4; ++nt)
                        acc[mt][nt] = __builtin_amdgcn_mfma_f32_16x16x32_bf16(af[mt], bf[nt], acc[mt][nt], 0, 0, 0);
            }
            __syncthreads();   // guards s_b restage AND s_h overwrite below
        }
        // write h(layer+1) over s_h
        #pragma unroll
        for (int mt = 0; mt < 4; ++mt) {
            int obase = wave * 64 + mt * 16 + quad * 4;
            float v0 = bp[obase], v1 = bp[obase + 1], v2 = bp[obase + 2], v3 = bp[obase + 3];
            int clow = mt * 2 + (quad >> 1), sub = (quad & 1) * 4;
            #pragma unroll
            for (int nt = 0; nt < 4; ++nt) {
                int row = nt * 16 + l15;
                int pos = wave * 8 + (clow ^ (row & 7));
                floatx4 v = acc[mt][nt];
                uint2 w;
                w.x = pk2(fmaxf(v[0] + v0, 0.f), fmaxf(v[1] + v1, 0.f));
                w.y = pk2(fmaxf(v[2] + v2, 0.f), fmaxf(v[3] + v3, 0.f));
                *(uint2*)&s_h[row * 256 + pos * 8 + sub] = w;
            }
        }
        __syncthreads();
    }

    // ================= fcf: A=WfB[32][256], B=h3 rows; fp32 out =================
    // stage WfB (16 KB) into s_b (linear copy, already swizzled): chunk cbase+lane per lane
    #pragma unroll
    for (int i = 0; i < 4; ++i) {
        int cbase = i * 256 + wave * 64;   // 16B chunks
        gload_lds16(WfB + (long long)(cbase + lane) * 8, &s_b[cbase * 8]);
    }
    __syncthreads();

    floatx4 accf[2] = {};
    const int myrow = wave * 16 + l15;       // this wave covers rows wave*16..+15
    #pragma unroll
    for (int w8 = 0; w8 < 8; ++w8) {         // K = 256 = 8 windows of 32
        int chi = w8 >> 1, clo = (w8 & 1) * 4 + quad;
        short8 bfr = *(const short8*)&s_h[myrow * 256 + (chi * 8 + (clo ^ (myrow & 7))) * 8];
        #pragma unroll
        for (int mt = 0; mt < 2; ++mt) {
            int o = mt * 16 + l15;
            short8 afr = *(const short8*)&s_b[o * 256 + (chi * 8 + (clo ^ (o & 7))) * 8];
            accf[mt] = __builtin_amdgcn_mfma_f32_16x16x32_bf16(afr, bfr, accf[mt], 0, 0, 0);
        }
    }
    // out[grow][o], o = mt*16 + quad*4 + r, row = wave*16 + l15
    const int grow = row0 + m0 + myrow;
    if (grow < NPATCH) {
        #pragma unroll
        for (int mt = 0; mt < 2; ++mt) {
            #pragma unroll
            for (int r = 0; r < 4; ++r) {
                int o = mt * 16 + quad * 4 + r;
                if (o < 27)
                    out[(long long)grow * 27 + o] = accf[mt][r] + bf_[o];
            }
        }
    }
}

extern "C" void kernel_launch(void* const* d_in, const int* in_sizes, int n_in,
                              void* d_out, int out_size, void* d_ws, size_t ws_size,
                              hipStream_t stream) {
    const float* images = (const float*)d_in[0];
    const float* c1w = (const float*)d_in[1];
    const float* c1b = (const float*)d_in[2];
    const float* c2w = (const float*)d_in[3];
    const float* c2b = (const float*)d_in[4];
    const float* f1w = (const float*)d_in[5];
    const float* f1b = (const float*)d_in[6];
    const float* f2w = (const float*)d_in[7];
    const float* f2b_ = (const float*)d_in[8];
    const float* f3w = (const float*)d_in[9];
    const float* f3b = (const float*)d_in[10];
    const float* ffw = (const float*)d_in[11];
    const float* ffb = (const float*)d_in[12];

    // ws: [W1][W2][W3][W1T][W2T][WfB][X]
    const long long W1_E = 327680, W2_E = 65536, W3_E = 65536;
    const long long W1T_E = 1024, W2T_E = 9216, WF_E = 8192;
    const long long WB = (W1_E + W2_E + W3_E + W1T_E + W2T_E + WF_E) * 2;  // 954368
    char* ws = (char*)d_ws;
    unsigned short* W1  = (unsigned short*)ws;
    unsigned short* W2  = W1 + W1_E;
    unsigned short* W3  = W2 + W2_E;
    unsigned short* W1T = W3 + W3_E;
    unsigned short* W2T = W1T + W1T_E;
    unsigned short* WfB = W2T + W2T_E;
    unsigned short* X   = (unsigned short*)(ws + WB);

    // per 128-row block: X only = 327680 B
    long long avail = (long long)ws_size - WB - 256;
    int nb_max = (int)(avail / 327680LL);
    if (nb_max < 1) nb_max = 1;
    if (nb_max > NBLK) nb_max = NBLK;
    int nchunks = (NBLK + nb_max - 1) / nb_max;
    int nb_even = (NBLK + nchunks - 1) / nchunks;

    prep<<<1864, 256, 0, stream>>>(f1w, f2w, f3w, c1w, c2w, ffw, W1, W2, W3, W1T, W2T, WfB);

    for (int b0 = 0; b0 < NBLK; b0 += nb_even) {
        int nb = NBLK - b0; if (nb > nb_even) nb = nb_even;
        int row0 = b0 * 128;
        int rows = nb * 128;

        conv_mfma<<<rows / 8, 256, 0, stream>>>(images, W1T, c1b, W2T, c2b, X, row0);
        fc_all<<<rows / 64, 256, 0, stream>>>(X, W1, W2, W3, WfB,
                                              f1b, f2b_, f3b, ffb, (float*)d_out, row0);
    }
}